// Round 6
// baseline (10615.093 us; speedup 1.0000x reference)
//
#include <hip/hip_runtime.h>
#include <math.h>

#define N    5000
#define E    4
#define H    64
#define PV   300
#define RD   64
#define NS_  8
#define SP_  6
#define NI   (RD + NS_ + SP_)   // 78
#define GH   (2 * H)            // 128
#define MSGW (2 * E * H)        // 512
#define CAP  128
#define REPB 4                  // instrumentation: k_build scan repeat
#define REPG 16                 // instrumentation: k_gru compute repeat
#define REPH 16                 // instrumentation: k_hs compute repeat

__device__ __forceinline__ float wsum(float v) {
    v += __shfl_xor(v, 32, 64);
    v += __shfl_xor(v, 16, 64);
    v += __shfl_xor(v, 8, 64);
    v += __shfl_xor(v, 4, 64);
    v += __shfl_xor(v, 2, 64);
    v += __shfl_xor(v, 1, 64);
    return v;
}

// ---------------------------------------------------------------------------
// Kz: zero the count arrays
// ---------------------------------------------------------------------------
__global__ __launch_bounds__(256) void k_zero(int4* __restrict__ p) {
    const int i = blockIdx.x * 256 + threadIdx.x;
    if (i < (2 * E * N) / 4) p[i] = make_int4(0, 0, 0, 0);
}

// ---------------------------------------------------------------------------
// K0: node init (not instrumented; small)
// ---------------------------------------------------------------------------
__global__ __launch_bounds__(64) void k_init(
    const float* __restrict__ NV, const float* __restrict__ NSt,
    const float* __restrict__ SPos, const float* __restrict__ Wred,
    const float* __restrict__ bred, const float* __restrict__ Winit,
    const float* __restrict__ binit, float* __restrict__ h)
{
    __shared__ float nv[4 * PV];
    __shared__ float ni[4 * NI];
    const int n0 = blockIdx.x * 4;
    const int j = threadIdx.x;

    for (int idx = j; idx < 4 * PV; idx += 64) nv[idx] = NV[(size_t)n0 * PV + idx];
    __syncthreads();

    float acc[4];
    {
        const float br = bred[j];
        #pragma unroll
        for (int nn = 0; nn < 4; ++nn) acc[nn] = br;
    }
    for (int k = 0; k < PV; ++k) {
        const float w = Wred[k * RD + j];
        #pragma unroll
        for (int nn = 0; nn < 4; ++nn) acc[nn] += nv[nn * PV + k] * w;
    }
    #pragma unroll
    for (int nn = 0; nn < 4; ++nn) ni[nn * NI + j] = tanhf(acc[nn]);
    if (j < NS_) {
        #pragma unroll
        for (int nn = 0; nn < 4; ++nn) ni[nn * NI + RD + j] = NSt[(size_t)(n0 + nn) * NS_ + j];
    }
    if (j < SP_) {
        #pragma unroll
        for (int nn = 0; nn < 4; ++nn) ni[nn * NI + RD + NS_ + j] = SPos[(size_t)(n0 + nn) * SP_ + j];
    }
    __syncthreads();

    float a2[4];
    {
        const float bi = binit[j];
        #pragma unroll
        for (int nn = 0; nn < 4; ++nn) a2[nn] = bi;
    }
    for (int k = 0; k < NI; ++k) {
        const float w = Winit[k * H + j];
        #pragma unroll
        for (int nn = 0; nn < 4; ++nn) a2[nn] += ni[nn * NI + k] * w;
    }
    #pragma unroll
    for (int nn = 0; nn < 4; ++nn) h[(size_t)(n0 + nn) * H + j] = tanhf(a2[nn]);
}

// ---------------------------------------------------------------------------
// K1: build lists — INSTRUMENTED: scan phase repeated REPB times (s_cnt reset
// per pass; opaque offset defeats load hoisting; last pass's s_cols used).
// ---------------------------------------------------------------------------
__global__ __launch_bounds__(256) void k_build(
    const float* __restrict__ A, int* __restrict__ cnt_out, int* __restrict__ cnt_in,
    unsigned short* __restrict__ idx_out, unsigned short* __restrict__ idx_in)
{
    const int r = blockIdx.x;          // e*N + n
    const int e = r / N;
    const int n = r - e * N;
    __shared__ int s_cnt;
    __shared__ int s_cols[CAP];

    const float4* row = (const float4*)(A + (size_t)r * N);
    const int lane = threadIdx.x & 63;
    int roff = 0;
    #pragma unroll 1
    for (int rep = 0; rep < REPB; ++rep) {
        asm volatile("" : "+v"(roff));
        if (threadIdx.x == 0) s_cnt = 0;
        __syncthreads();
        const float4* row2 = row + roff;
        #pragma unroll
        for (int it = 0; it < 5; ++it) {
            const int c = threadIdx.x + it * 256;
            float4 v = make_float4(0.f, 0.f, 0.f, 0.f);
            if (c < N / 4) v = row2[c];
            #pragma unroll
            for (int comp = 0; comp < 4; ++comp) {
                const float val = (comp == 0) ? v.x : (comp == 1) ? v.y : (comp == 2) ? v.z : v.w;
                const bool p = (val != 0.f);
                const unsigned long long m = __ballot(p);
                if (m) {
                    int base = 0;
                    if (lane == 0) base = atomicAdd(&s_cnt, (int)__popcll(m));
                    base = __shfl(base, 0, 64);
                    if (p) {
                        const int pos = base + (int)__popcll(m & ((1ull << lane) - 1ull));
                        if (pos < CAP) s_cols[pos] = 4 * c + comp;
                    }
                }
            }
        }
        __syncthreads();
    }
    const int cnt = min(s_cnt, CAP);
    if (threadIdx.x == 0) cnt_out[r] = cnt;
    for (int i = threadIdx.x; i < cnt; i += 256)
        idx_out[(size_t)r * CAP + i] = (unsigned short)s_cols[i];
    for (int i = threadIdx.x; i < cnt; i += 256) {
        const int m = s_cols[i];
        const int p = atomicAdd(&cnt_in[e * N + m], 1);
        if (p < CAP) idx_in[(size_t)(e * N + m) * CAP + p] = (unsigned short)n;
    }
}

// ---------------------------------------------------------------------------
// K2: hs GEMMs — INSTRUMENTED: compute repeated REPH times (opaque bias).
// ---------------------------------------------------------------------------
__global__ __launch_bounds__(256) void k_hs(
    const float* __restrict__ h, const float* __restrict__ Wout,
    const float* __restrict__ bout, const float* __restrict__ Win,
    const float* __restrict__ bin, float* __restrict__ hs_out,
    float* __restrict__ hs_in)
{
    __shared__ float hsd[8 * H];
    const int n0 = blockIdx.x * 8;
    const int tid = threadIdx.x;
    const int e = tid >> 6, j = tid & 63;

    for (int idx = tid; idx < 8 * H; idx += 256) hsd[idx] = h[(size_t)n0 * H + idx];
    __syncthreads();

    #pragma unroll 1
    for (int rep = 0; rep < REPH; ++rep) {
        float aO[8], aI[8];
        {
            float bO = bout[e * H + j], bI = bin[e * H + j];
            asm volatile("" : "+v"(bO), "+v"(bI));
            #pragma unroll
            for (int nn = 0; nn < 8; ++nn) { aO[nn] = bO; aI[nn] = bI; }
        }
        for (int k = 0; k < H; ++k) {
            const float wo = Wout[(e * H + k) * H + j];
            const float wi = Win[(e * H + k) * H + j];
            #pragma unroll
            for (int nn = 0; nn < 8; ++nn) {
                const float hv = hsd[nn * H + k];
                aO[nn] += hv * wo;
                aI[nn] += hv * wi;
            }
        }
        #pragma unroll
        for (int nn = 0; nn < 8; ++nn) {
            hs_out[((size_t)e * N + n0 + nn) * H + j] = tanhf(aO[nn]);
            hs_in[((size_t)e * N + n0 + nn) * H + j]  = tanhf(aI[nn]);
        }
    }
}

// ---------------------------------------------------------------------------
// K3: sparse message aggregation (single pass — known T ≈ 42 µs).
// ---------------------------------------------------------------------------
__global__ __launch_bounds__(512) void k_msg(
    const float* __restrict__ hs_out, const float* __restrict__ hs_in,
    const int* __restrict__ cnt_out, const int* __restrict__ cnt_in,
    const unsigned short* __restrict__ idx_out, const unsigned short* __restrict__ idx_in,
    float* __restrict__ msg)
{
    const int n = blockIdx.x;
    const int tid = threadIdx.x;
    const int wv = tid >> 6;             // 0..7
    const int dir = wv >> 2;             // 0=out, 1=in
    const int e = wv & 3;
    const int lane = tid & 63;
    const int g = lane >> 4;             // row-group 0..3
    const int l = lane & 15;             // float4 column within row

    const float4* hs4 = (const float4*)((dir ? hs_in : hs_out) + (size_t)e * N * H);
    const int* cnt = dir ? cnt_in : cnt_out;
    const unsigned short* idx = dir ? idx_in : idx_out;

    const int r = e * N + n;
    const int c = min(cnt[r], CAP);
    const unsigned short* lst = idx + (size_t)r * CAP;

    float ax = 0.f, ay = 0.f, az = 0.f, aw = 0.f;
    int i = g;
    for (; i + 12 < c; i += 16) {
        const int m0 = lst[i];
        const int m1 = lst[i + 4];
        const int m2 = lst[i + 8];
        const int m3 = lst[i + 12];
        const float4 v0 = hs4[(size_t)m0 * (H / 4) + l];
        const float4 v1 = hs4[(size_t)m1 * (H / 4) + l];
        const float4 v2 = hs4[(size_t)m2 * (H / 4) + l];
        const float4 v3 = hs4[(size_t)m3 * (H / 4) + l];
        ax += (v0.x + v1.x) + (v2.x + v3.x);
        ay += (v0.y + v1.y) + (v2.y + v3.y);
        az += (v0.z + v1.z) + (v2.z + v3.z);
        aw += (v0.w + v1.w) + (v2.w + v3.w);
    }
    for (; i < c; i += 4) {
        const float4 v = hs4[(size_t)lst[i] * (H / 4) + l];
        ax += v.x; ay += v.y; az += v.z; aw += v.w;
    }

    ax += __shfl_xor(ax, 16, 64); ay += __shfl_xor(ay, 16, 64);
    az += __shfl_xor(az, 16, 64); aw += __shfl_xor(aw, 16, 64);
    ax += __shfl_xor(ax, 32, 64); ay += __shfl_xor(ay, 32, 64);
    az += __shfl_xor(az, 32, 64); aw += __shfl_xor(aw, 32, 64);

    if (g == 0) {
        float4* mdst = (float4*)msg;
        mdst[(size_t)n * (MSGW / 4) + dir * (E * H / 4) + e * (H / 4) + l] =
            make_float4(ax, ay, az, aw);
    }
}

// ---------------------------------------------------------------------------
// K4: fused GRU — INSTRUMENTED: compute repeated REPG times (opaque bias).
// ---------------------------------------------------------------------------
__global__ __launch_bounds__(256) void k_gru(
    const float* __restrict__ msg, const float* __restrict__ h,
    const float* __restrict__ Wih_rz, const float* __restrict__ bih_rz,
    const float* __restrict__ Whh_rz, const float* __restrict__ bhh_rz,
    const float* __restrict__ Wih_c, const float* __restrict__ bih_c,
    const float* __restrict__ Whh_c, const float* __restrict__ bhh_c,
    const float* __restrict__ g_i2h, const float* __restrict__ be_i2h,
    const float* __restrict__ g_h2h, const float* __restrict__ be_h2h,
    const float* __restrict__ g_ci, const float* __restrict__ be_ci,
    const float* __restrict__ g_ch, const float* __restrict__ be_ch,
    float* __restrict__ h_out)
{
    __shared__ float ms[8 * MSGW];   // 16 KB
    __shared__ float hsd[8 * H];     // 2 KB
    const int n0 = blockIdx.x * 8;
    const int tid = threadIdx.x;
    const int j = tid & 63;
    const int wv = tid >> 6;         // 0..3
    const int nn0 = wv * 2;          // this wave owns nodes nn0, nn0+1

    {   // stage msg + h
        const float4* msrc = (const float4*)(msg + (size_t)n0 * MSGW);
        float4* mdst = (float4*)ms;
        for (int idx = tid; idx < 8 * MSGW / 4; idx += 256) mdst[idx] = msrc[idx];
        const float4* hsrc = (const float4*)(h + (size_t)n0 * H);
        float4* hdst = (float4*)hsd;
        for (int idx = tid; idx < 8 * H / 4; idx += 256) hdst[idx] = hsrc[idx];
    }
    __syncthreads();

    #pragma unroll 1
    for (int rep = 0; rep < REPG; ++rep) {
        float a0[2], a1[2], b0[2], b1[2];
        {
            float v0 = bih_rz[j], v1 = bih_rz[H + j];
            asm volatile("" : "+v"(v0), "+v"(v1));
            #pragma unroll
            for (int nn = 0; nn < 2; ++nn) { a0[nn] = v0; a1[nn] = v1; }
        }
        for (int k = 0; k < MSGW; ++k) {
            const float w0 = Wih_rz[k * GH + j];
            const float w1 = Wih_rz[k * GH + H + j];
            #pragma unroll
            for (int nn = 0; nn < 2; ++nn) {
                const float mv = ms[(nn0 + nn) * MSGW + k];
                a0[nn] += mv * w0;
                a1[nn] += mv * w1;
            }
        }
        {
            const float v0 = bhh_rz[j], v1 = bhh_rz[H + j];
            #pragma unroll
            for (int nn = 0; nn < 2; ++nn) { b0[nn] = v0; b1[nn] = v1; }
        }
        for (int k = 0; k < H; ++k) {
            const float w0 = Whh_rz[k * GH + j];
            const float w1 = Whh_rz[k * GH + H + j];
            #pragma unroll
            for (int nn = 0; nn < 2; ++nn) {
                const float hv = hsd[(nn0 + nn) * H + k];
                b0[nn] += hv * w0;
                b1[nn] += hv * w1;
            }
        }

        const float gi0 = g_i2h[j], gi1 = g_i2h[H + j], bi0 = be_i2h[j], bi1 = be_i2h[H + j];
        const float gh0 = g_h2h[j], gh1 = g_h2h[H + j], bh0 = be_h2h[j], bh1 = be_h2h[H + j];
        float r_[2], z_[2];
        #pragma unroll
        for (int nn = 0; nn < 2; ++nn) {
            float s  = wsum(a0[nn] + a1[nn]);
            float q  = wsum(a0[nn] * a0[nn] + a1[nn] * a1[nn]);
            float mn = s * (1.f / GH);
            float vr = q * (1.f / GH) - mn * mn;
            float rs = rsqrtf(vr + 1e-5f);
            float x0 = (a0[nn] - mn) * rs * gi0 + bi0;
            float x1 = (a1[nn] - mn) * rs * gi1 + bi1;
            float s2  = wsum(b0[nn] + b1[nn]);
            float q2  = wsum(b0[nn] * b0[nn] + b1[nn] * b1[nn]);
            float mn2 = s2 * (1.f / GH);
            float vr2 = q2 * (1.f / GH) - mn2 * mn2;
            float rs2 = rsqrtf(vr2 + 1e-5f);
            float y0 = (b0[nn] - mn2) * rs2 * gh0 + bh0;
            float y1 = (b1[nn] - mn2) * rs2 * gh1 + bh1;
            r_[nn] = 1.f / (1.f + expf(-(x0 + y0)));
            z_[nn] = 1.f / (1.f + expf(-(x1 + y1)));
        }

        float c0[2], ch[2];
        {
            const float v = bih_c[j];
            #pragma unroll
            for (int nn = 0; nn < 2; ++nn) c0[nn] = v;
        }
        for (int k = 0; k < MSGW; ++k) {
            const float w = Wih_c[k * H + j];
            #pragma unroll
            for (int nn = 0; nn < 2; ++nn) c0[nn] += ms[(nn0 + nn) * MSGW + k] * w;
        }
        {
            const float v = bhh_c[j];
            #pragma unroll
            for (int nn = 0; nn < 2; ++nn) ch[nn] = v;
        }
        for (int k = 0; k < H; ++k) {
            const float w = Whh_c[k * H + j];
            #pragma unroll
            for (int nn = 0; nn < 2; ++nn) ch[nn] += hsd[(nn0 + nn) * H + k] * w;
        }

        const float gci = g_ci[j], bci = be_ci[j], gchv = g_ch[j], bchv = be_ch[j];
        #pragma unroll
        for (int nn = 0; nn < 2; ++nn) {
            float s  = wsum(c0[nn]);
            float q  = wsum(c0[nn] * c0[nn]);
            float mn = s * (1.f / H);
            float vr = q * (1.f / H) - mn * mn;
            float rs = rsqrtf(vr + 1e-5f);
            float xc = (c0[nn] - mn) * rs * gci + bci;
            float s2  = wsum(ch[nn]);
            float q2  = wsum(ch[nn] * ch[nn]);
            float mn2 = s2 * (1.f / H);
            float vr2 = q2 * (1.f / H) - mn2 * mn2;
            float rs2 = rsqrtf(vr2 + 1e-5f);
            float hc = (ch[nn] - mn2) * rs2 * gchv + bchv;
            float c  = tanhf(xc + r_[nn] * hc);
            const float hp = hsd[(nn0 + nn) * H + j];
            h_out[(size_t)(n0 + nn0 + nn) * H + j] = z_[nn] * hp + (1.f - z_[nn]) * c;
        }
    }
}

// ---------------------------------------------------------------------------
extern "C" void kernel_launch(void* const* d_in, const int* in_sizes, int n_in,
                              void* d_out, int out_size, void* d_ws, size_t ws_size,
                              hipStream_t stream)
{
    const float* A      = (const float*)d_in[0];
    const float* nstate = (const float*)d_in[1];
    // d_in[2] node_ids unused
    const float* nvec   = (const float*)d_in[3];
    const float* nsp    = (const float*)d_in[4];
    const float* Wred   = (const float*)d_in[5];
    const float* bred   = (const float*)d_in[6];
    const float* Winit  = (const float*)d_in[7];
    const float* binit  = (const float*)d_in[8];
    const float* Wout   = (const float*)d_in[9];
    const float* bout   = (const float*)d_in[10];
    const float* Wine   = (const float*)d_in[11];
    const float* bine   = (const float*)d_in[12];
    const float* Wih_rz = (const float*)d_in[13];
    const float* bih_rz = (const float*)d_in[14];
    const float* Whh_rz = (const float*)d_in[15];
    const float* bhh_rz = (const float*)d_in[16];
    const float* Wih_c  = (const float*)d_in[17];
    const float* bih_c  = (const float*)d_in[18];
    const float* Whh_c  = (const float*)d_in[19];
    const float* bhh_c  = (const float*)d_in[20];
    const float* g_i2h  = (const float*)d_in[21];
    const float* be_i2h = (const float*)d_in[22];
    const float* g_h2h  = (const float*)d_in[23];
    const float* be_h2h = (const float*)d_in[24];
    const float* g_ci   = (const float*)d_in[25];
    const float* be_ci  = (const float*)d_in[26];
    const float* g_ch   = (const float*)d_in[27];
    const float* be_ch  = (const float*)d_in[28];

    char* ws = (char*)d_ws;
    size_t off = 0;
    auto alloc = [&](size_t bytes) {
        void* p = ws + off;
        off += (bytes + 255) & ~(size_t)255;
        return p;
    };
    float* h0  = (float*)alloc((size_t)N * H * 4);
    float* h1  = (float*)alloc((size_t)N * H * 4);
    float* hsO = (float*)alloc((size_t)E * N * H * 4);
    float* hsI = (float*)alloc((size_t)E * N * H * 4);
    float* msg = (float*)alloc((size_t)N * MSGW * 4);
    int* cnts  = (int*)alloc((size_t)2 * E * N * 4);
    int* cnt_out = cnts;
    int* cnt_in  = cnts + E * N;
    unsigned short* idxO = (unsigned short*)alloc((size_t)E * N * CAP * 2);
    unsigned short* idxI = (unsigned short*)alloc((size_t)E * N * CAP * 2);

    k_zero<<<(2 * E * N / 4 + 255) / 256, 256, 0, stream>>>((int4*)cnts);
    k_init<<<N / 4, 64, 0, stream>>>(nvec, nstate, nsp, Wred, bred, Winit, binit, h0);
    k_build<<<E * N, 256, 0, stream>>>(A, cnt_out, cnt_in, idxO, idxI);

    const float* hc = h0;
    for (int t = 0; t < 2; ++t) {
        k_hs<<<N / 8, 256, 0, stream>>>(hc, Wout, bout, Wine, bine, hsO, hsI);
        k_msg<<<N, 512, 0, stream>>>(hsO, hsI, cnt_out, cnt_in, idxO, idxI, msg);
        float* hn = (t == 1) ? (float*)d_out : h1;
        k_gru<<<N / 8, 256, 0, stream>>>(msg, hc, Wih_rz, bih_rz, Whh_rz, bhh_rz,
                                         Wih_c, bih_c, Whh_c, bhh_c,
                                         g_i2h, be_i2h, g_h2h, be_h2h,
                                         g_ci, be_ci, g_ch, be_ch, hn);
        hc = hn;
    }
}

// Round 7
// 488.343 us; speedup vs baseline: 21.7370x; 21.7370x over previous
//
#include <hip/hip_runtime.h>
#include <math.h>

#define N    5000
#define E    4
#define H    64
#define PV   300
#define RD   64
#define NS_  8
#define SP_  6
#define NI   (RD + NS_ + SP_)   // 78
#define GH   (2 * H)            // 128
#define MSGW (2 * E * H)        // 512
#define CAP  128
#define NPB  16                 // nodes per k_gru block

__device__ __forceinline__ float wsum(float v) {
    v += __shfl_xor(v, 32, 64);
    v += __shfl_xor(v, 16, 64);
    v += __shfl_xor(v, 8, 64);
    v += __shfl_xor(v, 4, 64);
    v += __shfl_xor(v, 2, 64);
    v += __shfl_xor(v, 1, 64);
    return v;
}

// ---------------------------------------------------------------------------
// Kz: zero the count arrays
// ---------------------------------------------------------------------------
__global__ __launch_bounds__(256) void k_zero(int4* __restrict__ p) {
    const int i = blockIdx.x * 256 + threadIdx.x;
    if (i < (2 * E * N) / 4) p[i] = make_int4(0, 0, 0, 0);
}

// ---------------------------------------------------------------------------
// Kt: transpose the 4 GRU weight matrices so k_gru's K-loop loads are
// contiguous float4 per lane.  27 tiles of 64x64.
// ---------------------------------------------------------------------------
__global__ __launch_bounds__(256) void k_tr(
    const float* __restrict__ Wrz, const float* __restrict__ Wc,
    const float* __restrict__ Whrz, const float* __restrict__ Whc,
    float* __restrict__ Trz, float* __restrict__ Tc,
    float* __restrict__ Thrz, float* __restrict__ Thc)
{
    __shared__ float s[64][65];
    const int b = blockIdx.x;
    const float* src; float* dst; int K, C, kt, ct;
    if (b < 16)      { src = Wrz;  dst = Trz;  K = 512; C = 128; kt = b >> 1;  ct = b & 1; }
    else if (b < 24) { src = Wc;   dst = Tc;   K = 512; C = 64;  kt = b - 16;  ct = 0; }
    else if (b < 26) { src = Whrz; dst = Thrz; K = 64;  C = 128; kt = 0;       ct = b - 24; }
    else             { src = Whc;  dst = Thc;  K = 64;  C = 64;  kt = 0;       ct = 0; }
    const int tid = threadIdx.x;
    const int c = tid & 63, rg = tid >> 6;
    #pragma unroll
    for (int i = 0; i < 16; ++i) {
        const int r = rg * 16 + i;
        s[r][c] = src[(size_t)(kt * 64 + r) * C + ct * 64 + c];
    }
    __syncthreads();
    const int k = tid & 63;
    #pragma unroll
    for (int i = 0; i < 16; ++i) {
        const int cc = rg * 16 + i;
        dst[(size_t)(ct * 64 + cc) * K + kt * 64 + k] = s[k][cc];
    }
}

// ---------------------------------------------------------------------------
// K0: h0 = tanh(concat[tanh(nv@W_red+b_red), node_states, node_sp] @ W_init + b_init)
// ---------------------------------------------------------------------------
__global__ __launch_bounds__(64) void k_init(
    const float* __restrict__ NV, const float* __restrict__ NSt,
    const float* __restrict__ SPos, const float* __restrict__ Wred,
    const float* __restrict__ bred, const float* __restrict__ Winit,
    const float* __restrict__ binit, float* __restrict__ h)
{
    __shared__ float nv[4 * PV];
    __shared__ float ni[4 * NI];
    const int n0 = blockIdx.x * 4;
    const int j = threadIdx.x;

    for (int idx = j; idx < 4 * PV; idx += 64) nv[idx] = NV[(size_t)n0 * PV + idx];
    __syncthreads();

    float acc[4];
    {
        const float br = bred[j];
        #pragma unroll
        for (int nn = 0; nn < 4; ++nn) acc[nn] = br;
    }
    for (int k = 0; k < PV; ++k) {
        const float w = Wred[k * RD + j];
        #pragma unroll
        for (int nn = 0; nn < 4; ++nn) acc[nn] += nv[nn * PV + k] * w;
    }
    #pragma unroll
    for (int nn = 0; nn < 4; ++nn) ni[nn * NI + j] = tanhf(acc[nn]);
    if (j < NS_) {
        #pragma unroll
        for (int nn = 0; nn < 4; ++nn) ni[nn * NI + RD + j] = NSt[(size_t)(n0 + nn) * NS_ + j];
    }
    if (j < SP_) {
        #pragma unroll
        for (int nn = 0; nn < 4; ++nn) ni[nn * NI + RD + NS_ + j] = SPos[(size_t)(n0 + nn) * SP_ + j];
    }
    __syncthreads();

    float a2[4];
    {
        const float bi = binit[j];
        #pragma unroll
        for (int nn = 0; nn < 4; ++nn) a2[nn] = bi;
    }
    for (int k = 0; k < NI; ++k) {
        const float w = Winit[k * H + j];
        #pragma unroll
        for (int nn = 0; nn < 4; ++nn) a2[nn] += ni[nn * NI + k] * w;
    }
    #pragma unroll
    for (int nn = 0; nn < 4; ++nn) h[(size_t)(n0 + nn) * H + j] = tanhf(a2[nn]);
}

// ---------------------------------------------------------------------------
// K1: build out/in adjacency lists (wave-ballot compaction).
// ---------------------------------------------------------------------------
__global__ __launch_bounds__(256) void k_build(
    const float* __restrict__ A, int* __restrict__ cnt_out, int* __restrict__ cnt_in,
    unsigned short* __restrict__ idx_out, unsigned short* __restrict__ idx_in)
{
    const int r = blockIdx.x;          // e*N + n
    const int e = r / N;
    const int n = r - e * N;
    __shared__ int s_cnt;
    __shared__ int s_cols[CAP];
    if (threadIdx.x == 0) s_cnt = 0;
    __syncthreads();

    const float4* row = (const float4*)(A + (size_t)r * N);
    const int lane = threadIdx.x & 63;
    #pragma unroll
    for (int it = 0; it < 5; ++it) {
        const int c = threadIdx.x + it * 256;
        float4 v = make_float4(0.f, 0.f, 0.f, 0.f);
        if (c < N / 4) v = row[c];
        #pragma unroll
        for (int comp = 0; comp < 4; ++comp) {
            const float val = (comp == 0) ? v.x : (comp == 1) ? v.y : (comp == 2) ? v.z : v.w;
            const bool p = (val != 0.f);
            const unsigned long long m = __ballot(p);
            if (m) {
                int base = 0;
                if (lane == 0) base = atomicAdd(&s_cnt, (int)__popcll(m));
                base = __shfl(base, 0, 64);
                if (p) {
                    const int pos = base + (int)__popcll(m & ((1ull << lane) - 1ull));
                    if (pos < CAP) s_cols[pos] = 4 * c + comp;
                }
            }
        }
    }
    __syncthreads();
    const int cnt = min(s_cnt, CAP);
    if (threadIdx.x == 0) cnt_out[r] = cnt;
    for (int i = threadIdx.x; i < cnt; i += 256)
        idx_out[(size_t)r * CAP + i] = (unsigned short)s_cols[i];
    for (int i = threadIdx.x; i < cnt; i += 256) {
        const int m = s_cols[i];
        const int p = atomicAdd(&cnt_in[e * N + m], 1);
        if (p < CAP) idx_in[(size_t)(e * N + m) * CAP + p] = (unsigned short)n;
    }
}

// ---------------------------------------------------------------------------
// K2: hs_out/hs_in = tanh(h @ W_out/W_in + b). 8 nodes per 256-thread block.
// ---------------------------------------------------------------------------
__global__ __launch_bounds__(256) void k_hs(
    const float* __restrict__ h, const float* __restrict__ Wout,
    const float* __restrict__ bout, const float* __restrict__ Win,
    const float* __restrict__ bin, float* __restrict__ hs_out,
    float* __restrict__ hs_in)
{
    __shared__ float hsd[8 * H];
    const int n0 = blockIdx.x * 8;
    const int tid = threadIdx.x;
    const int e = tid >> 6, j = tid & 63;

    for (int idx = tid; idx < 8 * H; idx += 256) hsd[idx] = h[(size_t)n0 * H + idx];
    __syncthreads();

    float aO[8], aI[8];
    {
        const float bO = bout[e * H + j], bI = bin[e * H + j];
        #pragma unroll
        for (int nn = 0; nn < 8; ++nn) { aO[nn] = bO; aI[nn] = bI; }
    }
    for (int k = 0; k < H; ++k) {
        const float wo = Wout[(e * H + k) * H + j];
        const float wi = Win[(e * H + k) * H + j];
        #pragma unroll
        for (int nn = 0; nn < 8; ++nn) {
            const float hv = hsd[nn * H + k];
            aO[nn] += hv * wo;
            aI[nn] += hv * wi;
        }
    }
    #pragma unroll
    for (int nn = 0; nn < 8; ++nn) {
        hs_out[((size_t)e * N + n0 + nn) * H + j] = tanhf(aO[nn]);
        hs_in[((size_t)e * N + n0 + nn) * H + j]  = tanhf(aI[nn]);
    }
}

// ---------------------------------------------------------------------------
// K3: sparse message aggregation (single-pass best version).
// ---------------------------------------------------------------------------
__global__ __launch_bounds__(512) void k_msg(
    const float* __restrict__ hs_out, const float* __restrict__ hs_in,
    const int* __restrict__ cnt_out, const int* __restrict__ cnt_in,
    const unsigned short* __restrict__ idx_out, const unsigned short* __restrict__ idx_in,
    float* __restrict__ msg)
{
    const int n = blockIdx.x;
    const int tid = threadIdx.x;
    const int wv = tid >> 6;             // 0..7
    const int dir = wv >> 2;             // 0=out, 1=in
    const int e = wv & 3;
    const int lane = tid & 63;
    const int g = lane >> 4;             // row-group 0..3
    const int l = lane & 15;             // float4 column within row

    const float4* hs4 = (const float4*)((dir ? hs_in : hs_out) + (size_t)e * N * H);
    const int* cnt = dir ? cnt_in : cnt_out;
    const unsigned short* idx = dir ? idx_in : idx_out;

    const int r = e * N + n;
    const int c = min(cnt[r], CAP);
    const unsigned short* lst = idx + (size_t)r * CAP;

    float ax = 0.f, ay = 0.f, az = 0.f, aw = 0.f;
    int i = g;
    for (; i + 12 < c; i += 16) {
        const int m0 = lst[i];
        const int m1 = lst[i + 4];
        const int m2 = lst[i + 8];
        const int m3 = lst[i + 12];
        const float4 v0 = hs4[(size_t)m0 * (H / 4) + l];
        const float4 v1 = hs4[(size_t)m1 * (H / 4) + l];
        const float4 v2 = hs4[(size_t)m2 * (H / 4) + l];
        const float4 v3 = hs4[(size_t)m3 * (H / 4) + l];
        ax += (v0.x + v1.x) + (v2.x + v3.x);
        ay += (v0.y + v1.y) + (v2.y + v3.y);
        az += (v0.z + v1.z) + (v2.z + v3.z);
        aw += (v0.w + v1.w) + (v2.w + v3.w);
    }
    for (; i < c; i += 4) {
        const float4 v = hs4[(size_t)lst[i] * (H / 4) + l];
        ax += v.x; ay += v.y; az += v.z; aw += v.w;
    }

    ax += __shfl_xor(ax, 16, 64); ay += __shfl_xor(ay, 16, 64);
    az += __shfl_xor(az, 16, 64); aw += __shfl_xor(aw, 16, 64);
    ax += __shfl_xor(ax, 32, 64); ay += __shfl_xor(ay, 32, 64);
    az += __shfl_xor(az, 32, 64); aw += __shfl_xor(aw, 32, 64);

    if (g == 0) {
        float4* mdst = (float4*)msg;
        mdst[(size_t)n * (MSGW / 4) + dir * (E * H / 4) + e * (H / 4) + l] =
            make_float4(ax, ay, az, aw);
    }
}

// ---------------------------------------------------------------------------
// K4 v2: fused GRU.  16 nodes/block (4 per wave).  Weights are pre-transposed
// so lane j streams its column's weights as contiguous float4 over k
// (global_load_dwordx4) -- fixes the scalar-load latency wall (was ~110us,
// VALUBusy 5.9%).  msg/h staged in LDS, read as same-address b128 broadcasts.
// ---------------------------------------------------------------------------
__global__ __launch_bounds__(256) void k_gru(
    const float* __restrict__ msg, const float* __restrict__ h,
    const float* __restrict__ Trz, const float* __restrict__ Tc,
    const float* __restrict__ Thrz, const float* __restrict__ Thc,
    const float* __restrict__ bih_rz, const float* __restrict__ bhh_rz,
    const float* __restrict__ bih_c, const float* __restrict__ bhh_c,
    const float* __restrict__ g_i2h, const float* __restrict__ be_i2h,
    const float* __restrict__ g_h2h, const float* __restrict__ be_h2h,
    const float* __restrict__ g_ci, const float* __restrict__ be_ci,
    const float* __restrict__ g_ch, const float* __restrict__ be_ch,
    float* __restrict__ h_out)
{
    __shared__ float ms[NPB * MSGW];   // 32 KB
    __shared__ float hsd[NPB * H];     // 4 KB
    const int n0 = blockIdx.x * NPB;
    const int tid = threadIdx.x;
    const int j = tid & 63;
    const int wv = tid >> 6;
    const int nb = wv * 4;             // this wave's first node (of 4)

    {   // stage msg (16 nodes x 512) + h (16 x 64), zero-fill past N
        const float4* msrc = (const float4*)msg;
        float4* md = (float4*)ms;
        #pragma unroll
        for (int i = 0; i < 8; ++i) {
            const int idx = tid + i * 256;          // 0..2047
            const int n = n0 + (idx >> 7);
            float4 v = make_float4(0.f, 0.f, 0.f, 0.f);
            if (n < N) v = msrc[(size_t)n0 * (MSGW / 4) + idx];
            md[idx] = v;
        }
        const float4* hsrc = (const float4*)h;
        float4 v = make_float4(0.f, 0.f, 0.f, 0.f);
        const int n = n0 + (tid >> 4);
        if (n < N) v = hsrc[(size_t)n0 * (H / 4) + tid];
        ((float4*)hsd)[tid] = v;
    }
    __syncthreads();

    const float4* ms4 = (const float4*)ms;
    const float4* hs4 = (const float4*)hsd;

    // ---- x parts: a0 = msg@Wih_rz col j, a1 = col j+64, c0 = msg@Wih_c col j
    float a0[4], a1[4], c0[4];
    {
        const float v0 = bih_rz[j], v1 = bih_rz[H + j], vc = bih_c[j];
        #pragma unroll
        for (int i = 0; i < 4; ++i) { a0[i] = v0; a1[i] = v1; c0[i] = vc; }
    }
    {
        const float4* w0p = (const float4*)(Trz + (size_t)j * MSGW);
        const float4* w1p = (const float4*)(Trz + (size_t)(j + 64) * MSGW);
        const float4* wcp = (const float4*)(Tc + (size_t)j * MSGW);
        for (int kq = 0; kq < MSGW / 4; ++kq) {
            const float4 w0 = w0p[kq], w1 = w1p[kq], wc = wcp[kq];
            #pragma unroll
            for (int i = 0; i < 4; ++i) {
                const float4 mv = ms4[(nb + i) * (MSGW / 4) + kq];
                a0[i] += mv.x * w0.x; a0[i] += mv.y * w0.y;
                a0[i] += mv.z * w0.z; a0[i] += mv.w * w0.w;
                a1[i] += mv.x * w1.x; a1[i] += mv.y * w1.y;
                a1[i] += mv.z * w1.z; a1[i] += mv.w * w1.w;
                c0[i] += mv.x * wc.x; c0[i] += mv.y * wc.y;
                c0[i] += mv.z * wc.z; c0[i] += mv.w * wc.w;
            }
        }
    }

    // ---- h parts: b0,b1 = h@Whh_rz cols j/j+64, ch = h@Whh_c col j
    float b0[4], b1[4], ch[4];
    {
        const float v0 = bhh_rz[j], v1 = bhh_rz[H + j], vc = bhh_c[j];
        #pragma unroll
        for (int i = 0; i < 4; ++i) { b0[i] = v0; b1[i] = v1; ch[i] = vc; }
    }
    {
        const float4* w0p = (const float4*)(Thrz + (size_t)j * H);
        const float4* w1p = (const float4*)(Thrz + (size_t)(j + 64) * H);
        const float4* wcp = (const float4*)(Thc + (size_t)j * H);
        for (int kq = 0; kq < H / 4; ++kq) {
            const float4 w0 = w0p[kq], w1 = w1p[kq], wc = wcp[kq];
            #pragma unroll
            for (int i = 0; i < 4; ++i) {
                const float4 hv = hs4[(nb + i) * (H / 4) + kq];
                b0[i] += hv.x * w0.x; b0[i] += hv.y * w0.y;
                b0[i] += hv.z * w0.z; b0[i] += hv.w * w0.w;
                b1[i] += hv.x * w1.x; b1[i] += hv.y * w1.y;
                b1[i] += hv.z * w1.z; b1[i] += hv.w * w1.w;
                ch[i] += hv.x * wc.x; ch[i] += hv.y * wc.y;
                ch[i] += hv.z * wc.z; ch[i] += hv.w * wc.w;
            }
        }
    }

    // ---- gates + LNs (per node of this wave)
    const float gi0 = g_i2h[j], gi1 = g_i2h[H + j], bi0 = be_i2h[j], bi1 = be_i2h[H + j];
    const float gh0 = g_h2h[j], gh1 = g_h2h[H + j], bh0 = be_h2h[j], bh1 = be_h2h[H + j];
    const float gci = g_ci[j], bci = be_ci[j], gchv = g_ch[j], bchv = be_ch[j];

    #pragma unroll
    for (int i = 0; i < 4; ++i) {
        float s  = wsum(a0[i] + a1[i]);
        float q  = wsum(a0[i] * a0[i] + a1[i] * a1[i]);
        float mn = s * (1.f / GH);
        float vr = q * (1.f / GH) - mn * mn;
        float rs = rsqrtf(vr + 1e-5f);
        float x0 = (a0[i] - mn) * rs * gi0 + bi0;
        float x1 = (a1[i] - mn) * rs * gi1 + bi1;
        float s2  = wsum(b0[i] + b1[i]);
        float q2  = wsum(b0[i] * b0[i] + b1[i] * b1[i]);
        float mn2 = s2 * (1.f / GH);
        float vr2 = q2 * (1.f / GH) - mn2 * mn2;
        float rs2 = rsqrtf(vr2 + 1e-5f);
        float y0 = (b0[i] - mn2) * rs2 * gh0 + bh0;
        float y1 = (b1[i] - mn2) * rs2 * gh1 + bh1;
        const float r_ = 1.f / (1.f + expf(-(x0 + y0)));
        const float z_ = 1.f / (1.f + expf(-(x1 + y1)));

        float s3  = wsum(c0[i]);
        float q3  = wsum(c0[i] * c0[i]);
        float mn3 = s3 * (1.f / H);
        float vr3 = q3 * (1.f / H) - mn3 * mn3;
        float rs3 = rsqrtf(vr3 + 1e-5f);
        float xc = (c0[i] - mn3) * rs3 * gci + bci;
        float s4  = wsum(ch[i]);
        float q4  = wsum(ch[i] * ch[i]);
        float mn4 = s4 * (1.f / H);
        float vr4 = q4 * (1.f / H) - mn4 * mn4;
        float rs4 = rsqrtf(vr4 + 1e-5f);
        float hc = (ch[i] - mn4) * rs4 * gchv + bchv;
        float c  = tanhf(xc + r_ * hc);
        const float hp = hsd[(nb + i) * H + j];
        const int n = n0 + nb + i;
        if (n < N) h_out[(size_t)n * H + j] = z_ * hp + (1.f - z_) * c;
    }
}

// ---------------------------------------------------------------------------
extern "C" void kernel_launch(void* const* d_in, const int* in_sizes, int n_in,
                              void* d_out, int out_size, void* d_ws, size_t ws_size,
                              hipStream_t stream)
{
    const float* A      = (const float*)d_in[0];
    const float* nstate = (const float*)d_in[1];
    // d_in[2] node_ids unused
    const float* nvec   = (const float*)d_in[3];
    const float* nsp    = (const float*)d_in[4];
    const float* Wred   = (const float*)d_in[5];
    const float* bred   = (const float*)d_in[6];
    const float* Winit  = (const float*)d_in[7];
    const float* binit  = (const float*)d_in[8];
    const float* Wout   = (const float*)d_in[9];
    const float* bout   = (const float*)d_in[10];
    const float* Wine   = (const float*)d_in[11];
    const float* bine   = (const float*)d_in[12];
    const float* Wih_rz = (const float*)d_in[13];
    const float* bih_rz = (const float*)d_in[14];
    const float* Whh_rz = (const float*)d_in[15];
    const float* bhh_rz = (const float*)d_in[16];
    const float* Wih_c  = (const float*)d_in[17];
    const float* bih_c  = (const float*)d_in[18];
    const float* Whh_c  = (const float*)d_in[19];
    const float* bhh_c  = (const float*)d_in[20];
    const float* g_i2h  = (const float*)d_in[21];
    const float* be_i2h = (const float*)d_in[22];
    const float* g_h2h  = (const float*)d_in[23];
    const float* be_h2h = (const float*)d_in[24];
    const float* g_ci   = (const float*)d_in[25];
    const float* be_ci  = (const float*)d_in[26];
    const float* g_ch   = (const float*)d_in[27];
    const float* be_ch  = (const float*)d_in[28];

    char* ws = (char*)d_ws;
    size_t off = 0;
    auto alloc = [&](size_t bytes) {
        void* p = ws + off;
        off += (bytes + 255) & ~(size_t)255;
        return p;
    };
    float* h0  = (float*)alloc((size_t)N * H * 4);
    float* h1  = (float*)alloc((size_t)N * H * 4);
    float* hsO = (float*)alloc((size_t)E * N * H * 4);
    float* hsI = (float*)alloc((size_t)E * N * H * 4);
    float* msg = (float*)alloc((size_t)N * MSGW * 4);
    int* cnts  = (int*)alloc((size_t)2 * E * N * 4);
    int* cnt_out = cnts;
    int* cnt_in  = cnts + E * N;
    unsigned short* idxO = (unsigned short*)alloc((size_t)E * N * CAP * 2);
    unsigned short* idxI = (unsigned short*)alloc((size_t)E * N * CAP * 2);
    float* Trz  = (float*)alloc((size_t)GH * MSGW * 4);   // [128][512]
    float* Tc   = (float*)alloc((size_t)H * MSGW * 4);    // [64][512]
    float* Thrz = (float*)alloc((size_t)GH * H * 4);      // [128][64]
    float* Thc  = (float*)alloc((size_t)H * H * 4);       // [64][64]

    k_zero<<<(2 * E * N / 4 + 255) / 256, 256, 0, stream>>>((int4*)cnts);
    k_tr<<<27, 256, 0, stream>>>(Wih_rz, Wih_c, Whh_rz, Whh_c, Trz, Tc, Thrz, Thc);
    k_init<<<N / 4, 64, 0, stream>>>(nvec, nstate, nsp, Wred, bred, Winit, binit, h0);
    k_build<<<E * N, 256, 0, stream>>>(A, cnt_out, cnt_in, idxO, idxI);

    const float* hc = h0;
    for (int t = 0; t < 2; ++t) {
        k_hs<<<N / 8, 256, 0, stream>>>(hc, Wout, bout, Wine, bine, hsO, hsI);
        k_msg<<<N, 512, 0, stream>>>(hsO, hsI, cnt_out, cnt_in, idxO, idxI, msg);
        float* hn = (t == 1) ? (float*)d_out : h1;
        k_gru<<<(N + NPB - 1) / NPB, 256, 0, stream>>>(
            msg, hc, Trz, Tc, Thrz, Thc,
            bih_rz, bhh_rz, bih_c, bhh_c,
            g_i2h, be_i2h, g_h2h, be_h2h,
            g_ci, be_ci, g_ch, be_ch, hn);
        hc = hn;
    }
}

// Round 8
// 392.285 us; speedup vs baseline: 27.0596x; 1.2449x over previous
//
#include <hip/hip_runtime.h>
#include <math.h>

#define N    5000
#define E    4
#define H    64
#define PV   300
#define RD   64
#define NS_  8
#define SP_  6
#define NI   (RD + NS_ + SP_)   // 78
#define GH   (2 * H)            // 128
#define MSGW (2 * E * H)        // 512
#define CAP  128
#define NPB  16                 // nodes per k_gru block (4 per wave)

__device__ __forceinline__ float wsum(float v) {
    v += __shfl_xor(v, 32, 64);
    v += __shfl_xor(v, 16, 64);
    v += __shfl_xor(v, 8, 64);
    v += __shfl_xor(v, 4, 64);
    v += __shfl_xor(v, 2, 64);
    v += __shfl_xor(v, 1, 64);
    return v;
}

// ---------------------------------------------------------------------------
// Kz: zero the count arrays
// ---------------------------------------------------------------------------
__global__ __launch_bounds__(256) void k_zero(int4* __restrict__ p) {
    const int i = blockIdx.x * 256 + threadIdx.x;
    if (i < (2 * E * N) / 4) p[i] = make_int4(0, 0, 0, 0);
}

// ---------------------------------------------------------------------------
// K0: h0 = tanh(concat[tanh(nv@W_red+b_red), node_states, node_sp] @ W_init + b_init)
// ---------------------------------------------------------------------------
__global__ __launch_bounds__(64) void k_init(
    const float* __restrict__ NV, const float* __restrict__ NSt,
    const float* __restrict__ SPos, const float* __restrict__ Wred,
    const float* __restrict__ bred, const float* __restrict__ Winit,
    const float* __restrict__ binit, float* __restrict__ h)
{
    __shared__ float nv[4 * PV];
    __shared__ float ni[4 * NI];
    const int n0 = blockIdx.x * 4;
    const int j = threadIdx.x;

    for (int idx = j; idx < 4 * PV; idx += 64) nv[idx] = NV[(size_t)n0 * PV + idx];
    __syncthreads();

    float acc[4];
    {
        const float br = bred[j];
        #pragma unroll
        for (int nn = 0; nn < 4; ++nn) acc[nn] = br;
    }
    for (int k = 0; k < PV; ++k) {
        const float w = Wred[k * RD + j];
        #pragma unroll
        for (int nn = 0; nn < 4; ++nn) acc[nn] += nv[nn * PV + k] * w;
    }
    #pragma unroll
    for (int nn = 0; nn < 4; ++nn) ni[nn * NI + j] = tanhf(acc[nn]);
    if (j < NS_) {
        #pragma unroll
        for (int nn = 0; nn < 4; ++nn) ni[nn * NI + RD + j] = NSt[(size_t)(n0 + nn) * NS_ + j];
    }
    if (j < SP_) {
        #pragma unroll
        for (int nn = 0; nn < 4; ++nn) ni[nn * NI + RD + NS_ + j] = SPos[(size_t)(n0 + nn) * SP_ + j];
    }
    __syncthreads();

    float a2[4];
    {
        const float bi = binit[j];
        #pragma unroll
        for (int nn = 0; nn < 4; ++nn) a2[nn] = bi;
    }
    for (int k = 0; k < NI; ++k) {
        const float w = Winit[k * H + j];
        #pragma unroll
        for (int nn = 0; nn < 4; ++nn) a2[nn] += ni[nn * NI + k] * w;
    }
    #pragma unroll
    for (int nn = 0; nn < 4; ++nn) h[(size_t)(n0 + nn) * H + j] = tanhf(a2[nn]);
}

// ---------------------------------------------------------------------------
// K1: build out/in adjacency lists (wave-ballot compaction).
// ---------------------------------------------------------------------------
__global__ __launch_bounds__(256) void k_build(
    const float* __restrict__ A, int* __restrict__ cnt_out, int* __restrict__ cnt_in,
    unsigned short* __restrict__ idx_out, unsigned short* __restrict__ idx_in)
{
    const int r = blockIdx.x;          // e*N + n
    const int e = r / N;
    const int n = r - e * N;
    __shared__ int s_cnt;
    __shared__ int s_cols[CAP];
    if (threadIdx.x == 0) s_cnt = 0;
    __syncthreads();

    const float4* row = (const float4*)(A + (size_t)r * N);
    const int lane = threadIdx.x & 63;
    #pragma unroll
    for (int it = 0; it < 5; ++it) {
        const int c = threadIdx.x + it * 256;
        float4 v = make_float4(0.f, 0.f, 0.f, 0.f);
        if (c < N / 4) v = row[c];
        #pragma unroll
        for (int comp = 0; comp < 4; ++comp) {
            const float val = (comp == 0) ? v.x : (comp == 1) ? v.y : (comp == 2) ? v.z : v.w;
            const bool p = (val != 0.f);
            const unsigned long long m = __ballot(p);
            if (m) {
                int base = 0;
                if (lane == 0) base = atomicAdd(&s_cnt, (int)__popcll(m));
                base = __shfl(base, 0, 64);
                if (p) {
                    const int pos = base + (int)__popcll(m & ((1ull << lane) - 1ull));
                    if (pos < CAP) s_cols[pos] = 4 * c + comp;
                }
            }
        }
    }
    __syncthreads();
    const int cnt = min(s_cnt, CAP);
    if (threadIdx.x == 0) cnt_out[r] = cnt;
    for (int i = threadIdx.x; i < cnt; i += 256)
        idx_out[(size_t)r * CAP + i] = (unsigned short)s_cols[i];
    for (int i = threadIdx.x; i < cnt; i += 256) {
        const int m = s_cols[i];
        const int p = atomicAdd(&cnt_in[e * N + m], 1);
        if (p < CAP) idx_in[(size_t)(e * N + m) * CAP + p] = (unsigned short)n;
    }
}

// ---------------------------------------------------------------------------
// K2: hs_out/hs_in = tanh(h @ W_out/W_in + b). 8 nodes per 256-thread block.
// ---------------------------------------------------------------------------
__global__ __launch_bounds__(256) void k_hs(
    const float* __restrict__ h, const float* __restrict__ Wout,
    const float* __restrict__ bout, const float* __restrict__ Win,
    const float* __restrict__ bin, float* __restrict__ hs_out,
    float* __restrict__ hs_in)
{
    __shared__ float hsd[8 * H];
    const int n0 = blockIdx.x * 8;
    const int tid = threadIdx.x;
    const int e = tid >> 6, j = tid & 63;

    for (int idx = tid; idx < 8 * H; idx += 256) hsd[idx] = h[(size_t)n0 * H + idx];
    __syncthreads();

    float aO[8], aI[8];
    {
        const float bO = bout[e * H + j], bI = bin[e * H + j];
        #pragma unroll
        for (int nn = 0; nn < 8; ++nn) { aO[nn] = bO; aI[nn] = bI; }
    }
    for (int k = 0; k < H; ++k) {
        const float wo = Wout[(e * H + k) * H + j];
        const float wi = Win[(e * H + k) * H + j];
        #pragma unroll
        for (int nn = 0; nn < 8; ++nn) {
            const float hv = hsd[nn * H + k];
            aO[nn] += hv * wo;
            aI[nn] += hv * wi;
        }
    }
    #pragma unroll
    for (int nn = 0; nn < 8; ++nn) {
        hs_out[((size_t)e * N + n0 + nn) * H + j] = tanhf(aO[nn]);
        hs_in[((size_t)e * N + n0 + nn) * H + j]  = tanhf(aI[nn]);
    }
}

// ---------------------------------------------------------------------------
// K3: sparse message aggregation (single-pass best version).
// ---------------------------------------------------------------------------
__global__ __launch_bounds__(512) void k_msg(
    const float* __restrict__ hs_out, const float* __restrict__ hs_in,
    const int* __restrict__ cnt_out, const int* __restrict__ cnt_in,
    const unsigned short* __restrict__ idx_out, const unsigned short* __restrict__ idx_in,
    float* __restrict__ msg)
{
    const int n = blockIdx.x;
    const int tid = threadIdx.x;
    const int wv = tid >> 6;             // 0..7
    const int dir = wv >> 2;             // 0=out, 1=in
    const int e = wv & 3;
    const int lane = tid & 63;
    const int g = lane >> 4;             // row-group 0..3
    const int l = lane & 15;             // float4 column within row

    const float4* hs4 = (const float4*)((dir ? hs_in : hs_out) + (size_t)e * N * H);
    const int* cnt = dir ? cnt_in : cnt_out;
    const unsigned short* idx = dir ? idx_in : idx_out;

    const int r = e * N + n;
    const int c = min(cnt[r], CAP);
    const unsigned short* lst = idx + (size_t)r * CAP;

    float ax = 0.f, ay = 0.f, az = 0.f, aw = 0.f;
    int i = g;
    for (; i + 12 < c; i += 16) {
        const int m0 = lst[i];
        const int m1 = lst[i + 4];
        const int m2 = lst[i + 8];
        const int m3 = lst[i + 12];
        const float4 v0 = hs4[(size_t)m0 * (H / 4) + l];
        const float4 v1 = hs4[(size_t)m1 * (H / 4) + l];
        const float4 v2 = hs4[(size_t)m2 * (H / 4) + l];
        const float4 v3 = hs4[(size_t)m3 * (H / 4) + l];
        ax += (v0.x + v1.x) + (v2.x + v3.x);
        ay += (v0.y + v1.y) + (v2.y + v3.y);
        az += (v0.z + v1.z) + (v2.z + v3.z);
        aw += (v0.w + v1.w) + (v2.w + v3.w);
    }
    for (; i < c; i += 4) {
        const float4 v = hs4[(size_t)lst[i] * (H / 4) + l];
        ax += v.x; ay += v.y; az += v.z; aw += v.w;
    }

    ax += __shfl_xor(ax, 16, 64); ay += __shfl_xor(ay, 16, 64);
    az += __shfl_xor(az, 16, 64); aw += __shfl_xor(aw, 16, 64);
    ax += __shfl_xor(ax, 32, 64); ay += __shfl_xor(ay, 32, 64);
    az += __shfl_xor(az, 32, 64); aw += __shfl_xor(aw, 32, 64);

    if (g == 0) {
        float4* mdst = (float4*)msg;
        mdst[(size_t)n * (MSGW / 4) + dir * (E * H / 4) + e * (H / 4) + l] =
            make_float4(ax, ay, az, aw);
    }
}

// ---------------------------------------------------------------------------
// K4 v3: fused GRU. Coalesced W loads (original layout, lane j = output col),
// 4 nodes per wave (16/block), msg/h in LDS read as same-address float4
// broadcasts. Per 4-k group: 12 coalesced loads + 4 LDS b128 + 48 FMA.
// ---------------------------------------------------------------------------
__global__ __launch_bounds__(256) void k_gru(
    const float* __restrict__ msg, const float* __restrict__ h,
    const float* __restrict__ Wih_rz, const float* __restrict__ bih_rz,
    const float* __restrict__ Whh_rz, const float* __restrict__ bhh_rz,
    const float* __restrict__ Wih_c, const float* __restrict__ bih_c,
    const float* __restrict__ Whh_c, const float* __restrict__ bhh_c,
    const float* __restrict__ g_i2h, const float* __restrict__ be_i2h,
    const float* __restrict__ g_h2h, const float* __restrict__ be_h2h,
    const float* __restrict__ g_ci, const float* __restrict__ be_ci,
    const float* __restrict__ g_ch, const float* __restrict__ be_ch,
    float* __restrict__ h_out)
{
    __shared__ float ms[NPB * MSGW];   // 32 KB
    __shared__ float hsd[NPB * H];     // 4 KB
    const int n0 = blockIdx.x * NPB;
    const int tid = threadIdx.x;
    const int j = tid & 63;
    const int wv = tid >> 6;
    const int nb = wv * 4;             // this wave's first node (of 4)

    {   // stage msg (16 nodes x 512) + h (16 x 64), zero-fill past N
        const float4* msrc = (const float4*)msg;
        float4* md = (float4*)ms;
        #pragma unroll
        for (int i = 0; i < 8; ++i) {
            const int idx = tid + i * 256;          // 0..2047
            const int n = n0 + (idx >> 7);
            float4 v = make_float4(0.f, 0.f, 0.f, 0.f);
            if (n < N) v = msrc[(size_t)n0 * (MSGW / 4) + idx];
            md[idx] = v;
        }
        const float4* hsrc = (const float4*)h;
        float4 v = make_float4(0.f, 0.f, 0.f, 0.f);
        const int n = n0 + (tid >> 4);
        if (n < N) v = hsrc[(size_t)n0 * (H / 4) + tid];
        ((float4*)hsd)[tid] = v;
    }
    __syncthreads();

    const float4* ms4 = (const float4*)ms;
    const float4* hs4 = (const float4*)hsd;

    // ---- x parts: a0 = msg@Wih_rz col j, a1 = col j+64, c0 = msg@Wih_c col j
    float a0[4], a1[4], c0[4];
    {
        const float v0 = bih_rz[j], v1 = bih_rz[H + j], vc = bih_c[j];
        #pragma unroll
        for (int i = 0; i < 4; ++i) { a0[i] = v0; a1[i] = v1; c0[i] = vc; }
    }
    #pragma unroll 2
    for (int kq = 0; kq < MSGW / 4; ++kq) {
        float4 m[4];
        #pragma unroll
        for (int i = 0; i < 4; ++i) m[i] = ms4[(nb + i) * (MSGW / 4) + kq];
        #pragma unroll
        for (int u = 0; u < 4; ++u) {
            const int k = 4 * kq + u;
            const float w0 = Wih_rz[k * GH + j];
            const float w1 = Wih_rz[k * GH + H + j];
            const float wc = Wih_c[k * H + j];
            #pragma unroll
            for (int i = 0; i < 4; ++i) {
                const float mv = (u == 0) ? m[i].x : (u == 1) ? m[i].y : (u == 2) ? m[i].z : m[i].w;
                a0[i] += mv * w0;
                a1[i] += mv * w1;
                c0[i] += mv * wc;
            }
        }
    }

    // ---- h parts: b0,b1 = h@Whh_rz cols j/j+64, ch = h@Whh_c col j
    float b0[4], b1[4], ch[4];
    {
        const float v0 = bhh_rz[j], v1 = bhh_rz[H + j], vc = bhh_c[j];
        #pragma unroll
        for (int i = 0; i < 4; ++i) { b0[i] = v0; b1[i] = v1; ch[i] = vc; }
    }
    #pragma unroll 2
    for (int kq = 0; kq < H / 4; ++kq) {
        float4 m[4];
        #pragma unroll
        for (int i = 0; i < 4; ++i) m[i] = hs4[(nb + i) * (H / 4) + kq];
        #pragma unroll
        for (int u = 0; u < 4; ++u) {
            const int k = 4 * kq + u;
            const float w0 = Whh_rz[k * GH + j];
            const float w1 = Whh_rz[k * GH + H + j];
            const float wc = Whh_c[k * H + j];
            #pragma unroll
            for (int i = 0; i < 4; ++i) {
                const float hv = (u == 0) ? m[i].x : (u == 1) ? m[i].y : (u == 2) ? m[i].z : m[i].w;
                b0[i] += hv * w0;
                b1[i] += hv * w1;
                ch[i] += hv * wc;
            }
        }
    }

    // ---- gates + LNs (per node of this wave)
    const float gi0 = g_i2h[j], gi1 = g_i2h[H + j], bi0 = be_i2h[j], bi1 = be_i2h[H + j];
    const float gh0 = g_h2h[j], gh1 = g_h2h[H + j], bh0 = be_h2h[j], bh1 = be_h2h[H + j];
    const float gci = g_ci[j], bci = be_ci[j], gchv = g_ch[j], bchv = be_ch[j];

    #pragma unroll
    for (int i = 0; i < 4; ++i) {
        float s  = wsum(a0[i] + a1[i]);
        float q  = wsum(a0[i] * a0[i] + a1[i] * a1[i]);
        float mn = s * (1.f / GH);
        float vr = q * (1.f / GH) - mn * mn;
        float rs = rsqrtf(vr + 1e-5f);
        float x0 = (a0[i] - mn) * rs * gi0 + bi0;
        float x1 = (a1[i] - mn) * rs * gi1 + bi1;
        float s2  = wsum(b0[i] + b1[i]);
        float q2  = wsum(b0[i] * b0[i] + b1[i] * b1[i]);
        float mn2 = s2 * (1.f / GH);
        float vr2 = q2 * (1.f / GH) - mn2 * mn2;
        float rs2 = rsqrtf(vr2 + 1e-5f);
        float y0 = (b0[i] - mn2) * rs2 * gh0 + bh0;
        float y1 = (b1[i] - mn2) * rs2 * gh1 + bh1;
        const float r_ = 1.f / (1.f + expf(-(x0 + y0)));
        const float z_ = 1.f / (1.f + expf(-(x1 + y1)));

        float s3  = wsum(c0[i]);
        float q3  = wsum(c0[i] * c0[i]);
        float mn3 = s3 * (1.f / H);
        float vr3 = q3 * (1.f / H) - mn3 * mn3;
        float rs3 = rsqrtf(vr3 + 1e-5f);
        float xc = (c0[i] - mn3) * rs3 * gci + bci;
        float s4  = wsum(ch[i]);
        float q4  = wsum(ch[i] * ch[i]);
        float mn4 = s4 * (1.f / H);
        float vr4 = q4 * (1.f / H) - mn4 * mn4;
        float rs4 = rsqrtf(vr4 + 1e-5f);
        float hc = (ch[i] - mn4) * rs4 * gchv + bchv;
        float c  = tanhf(xc + r_ * hc);
        const float hp = hsd[(nb + i) * H + j];
        const int n = n0 + nb + i;
        if (n < N) h_out[(size_t)n * H + j] = z_ * hp + (1.f - z_) * c;
    }
}

// ---------------------------------------------------------------------------
extern "C" void kernel_launch(void* const* d_in, const int* in_sizes, int n_in,
                              void* d_out, int out_size, void* d_ws, size_t ws_size,
                              hipStream_t stream)
{
    const float* A      = (const float*)d_in[0];
    const float* nstate = (const float*)d_in[1];
    // d_in[2] node_ids unused
    const float* nvec   = (const float*)d_in[3];
    const float* nsp    = (const float*)d_in[4];
    const float* Wred   = (const float*)d_in[5];
    const float* bred   = (const float*)d_in[6];
    const float* Winit  = (const float*)d_in[7];
    const float* binit  = (const float*)d_in[8];
    const float* Wout   = (const float*)d_in[9];
    const float* bout   = (const float*)d_in[10];
    const float* Wine   = (const float*)d_in[11];
    const float* bine   = (const float*)d_in[12];
    const float* Wih_rz = (const float*)d_in[13];
    const float* bih_rz = (const float*)d_in[14];
    const float* Whh_rz = (const float*)d_in[15];
    const float* bhh_rz = (const float*)d_in[16];
    const float* Wih_c  = (const float*)d_in[17];
    const float* bih_c  = (const float*)d_in[18];
    const float* Whh_c  = (const float*)d_in[19];
    const float* bhh_c  = (const float*)d_in[20];
    const float* g_i2h  = (const float*)d_in[21];
    const float* be_i2h = (const float*)d_in[22];
    const float* g_h2h  = (const float*)d_in[23];
    const float* be_h2h = (const float*)d_in[24];
    const float* g_ci   = (const float*)d_in[25];
    const float* be_ci  = (const float*)d_in[26];
    const float* g_ch   = (const float*)d_in[27];
    const float* be_ch  = (const float*)d_in[28];

    char* ws = (char*)d_ws;
    size_t off = 0;
    auto alloc = [&](size_t bytes) {
        void* p = ws + off;
        off += (bytes + 255) & ~(size_t)255;
        return p;
    };
    float* h0  = (float*)alloc((size_t)N * H * 4);
    float* h1  = (float*)alloc((size_t)N * H * 4);
    float* hsO = (float*)alloc((size_t)E * N * H * 4);
    float* hsI = (float*)alloc((size_t)E * N * H * 4);
    float* msg = (float*)alloc((size_t)N * MSGW * 4);
    int* cnts  = (int*)alloc((size_t)2 * E * N * 4);
    int* cnt_out = cnts;
    int* cnt_in  = cnts + E * N;
    unsigned short* idxO = (unsigned short*)alloc((size_t)E * N * CAP * 2);
    unsigned short* idxI = (unsigned short*)alloc((size_t)E * N * CAP * 2);

    k_zero<<<(2 * E * N / 4 + 255) / 256, 256, 0, stream>>>((int4*)cnts);
    k_init<<<N / 4, 64, 0, stream>>>(nvec, nstate, nsp, Wred, bred, Winit, binit, h0);
    k_build<<<E * N, 256, 0, stream>>>(A, cnt_out, cnt_in, idxO, idxI);

    const float* hc = h0;
    for (int t = 0; t < 2; ++t) {
        k_hs<<<N / 8, 256, 0, stream>>>(hc, Wout, bout, Wine, bine, hsO, hsI);
        k_msg<<<N, 512, 0, stream>>>(hsO, hsI, cnt_out, cnt_in, idxO, idxI, msg);
        float* hn = (t == 1) ? (float*)d_out : h1;
        k_gru<<<(N + NPB - 1) / NPB, 256, 0, stream>>>(
            msg, hc, Wih_rz, bih_rz, Whh_rz, bhh_rz,
            Wih_c, bih_c, Whh_c, bhh_c,
            g_i2h, be_i2h, g_h2h, be_h2h,
            g_ci, be_ci, g_ch, be_ch, hn);
        hc = hn;
    }
}

// Round 9
// 348.467 us; speedup vs baseline: 30.4622x; 1.1257x over previous
//
#include <hip/hip_runtime.h>
#include <math.h>

#define N    5000
#define E    4
#define H    64
#define PV   300
#define RD   64
#define NS_  8
#define SP_  6
#define NI   (RD + NS_ + SP_)   // 78
#define GH   (2 * H)            // 128
#define MSGW (2 * E * H)        // 512
#define CAP  128
#define NPB  8                  // nodes per k_gru block (4 per wave, 2-way K split)

__device__ __forceinline__ float wsum(float v) {
    v += __shfl_xor(v, 32, 64);
    v += __shfl_xor(v, 16, 64);
    v += __shfl_xor(v, 8, 64);
    v += __shfl_xor(v, 4, 64);
    v += __shfl_xor(v, 2, 64);
    v += __shfl_xor(v, 1, 64);
    return v;
}

// ---------------------------------------------------------------------------
// Kz: zero the count arrays
// ---------------------------------------------------------------------------
__global__ __launch_bounds__(256) void k_zero(int4* __restrict__ p) {
    const int i = blockIdx.x * 256 + threadIdx.x;
    if (i < (2 * E * N) / 4) p[i] = make_int4(0, 0, 0, 0);
}

// ---------------------------------------------------------------------------
// K0: h0 = tanh(concat[tanh(nv@W_red+b_red), node_states, node_sp] @ W_init + b_init)
// ---------------------------------------------------------------------------
__global__ __launch_bounds__(64) void k_init(
    const float* __restrict__ NV, const float* __restrict__ NSt,
    const float* __restrict__ SPos, const float* __restrict__ Wred,
    const float* __restrict__ bred, const float* __restrict__ Winit,
    const float* __restrict__ binit, float* __restrict__ h)
{
    __shared__ float nv[4 * PV];
    __shared__ float ni[4 * NI];
    const int n0 = blockIdx.x * 4;
    const int j = threadIdx.x;

    for (int idx = j; idx < 4 * PV; idx += 64) nv[idx] = NV[(size_t)n0 * PV + idx];
    __syncthreads();

    float acc[4];
    {
        const float br = bred[j];
        #pragma unroll
        for (int nn = 0; nn < 4; ++nn) acc[nn] = br;
    }
    for (int k = 0; k < PV; ++k) {
        const float w = Wred[k * RD + j];
        #pragma unroll
        for (int nn = 0; nn < 4; ++nn) acc[nn] += nv[nn * PV + k] * w;
    }
    #pragma unroll
    for (int nn = 0; nn < 4; ++nn) ni[nn * NI + j] = tanhf(acc[nn]);
    if (j < NS_) {
        #pragma unroll
        for (int nn = 0; nn < 4; ++nn) ni[nn * NI + RD + j] = NSt[(size_t)(n0 + nn) * NS_ + j];
    }
    if (j < SP_) {
        #pragma unroll
        for (int nn = 0; nn < 4; ++nn) ni[nn * NI + RD + NS_ + j] = SPos[(size_t)(n0 + nn) * SP_ + j];
    }
    __syncthreads();

    float a2[4];
    {
        const float bi = binit[j];
        #pragma unroll
        for (int nn = 0; nn < 4; ++nn) a2[nn] = bi;
    }
    for (int k = 0; k < NI; ++k) {
        const float w = Winit[k * H + j];
        #pragma unroll
        for (int nn = 0; nn < 4; ++nn) a2[nn] += ni[nn * NI + k] * w;
    }
    #pragma unroll
    for (int nn = 0; nn < 4; ++nn) h[(size_t)(n0 + nn) * H + j] = tanhf(a2[nn]);
}

// ---------------------------------------------------------------------------
// K1: build out/in adjacency lists (wave-ballot compaction).
// ---------------------------------------------------------------------------
__global__ __launch_bounds__(256) void k_build(
    const float* __restrict__ A, int* __restrict__ cnt_out, int* __restrict__ cnt_in,
    unsigned short* __restrict__ idx_out, unsigned short* __restrict__ idx_in)
{
    const int r = blockIdx.x;          // e*N + n
    const int e = r / N;
    const int n = r - e * N;
    __shared__ int s_cnt;
    __shared__ int s_cols[CAP];
    if (threadIdx.x == 0) s_cnt = 0;
    __syncthreads();

    const float4* row = (const float4*)(A + (size_t)r * N);
    const int lane = threadIdx.x & 63;
    #pragma unroll
    for (int it = 0; it < 5; ++it) {
        const int c = threadIdx.x + it * 256;
        float4 v = make_float4(0.f, 0.f, 0.f, 0.f);
        if (c < N / 4) v = row[c];
        #pragma unroll
        for (int comp = 0; comp < 4; ++comp) {
            const float val = (comp == 0) ? v.x : (comp == 1) ? v.y : (comp == 2) ? v.z : v.w;
            const bool p = (val != 0.f);
            const unsigned long long m = __ballot(p);
            if (m) {
                int base = 0;
                if (lane == 0) base = atomicAdd(&s_cnt, (int)__popcll(m));
                base = __shfl(base, 0, 64);
                if (p) {
                    const int pos = base + (int)__popcll(m & ((1ull << lane) - 1ull));
                    if (pos < CAP) s_cols[pos] = 4 * c + comp;
                }
            }
        }
    }
    __syncthreads();
    const int cnt = min(s_cnt, CAP);
    if (threadIdx.x == 0) cnt_out[r] = cnt;
    for (int i = threadIdx.x; i < cnt; i += 256)
        idx_out[(size_t)r * CAP + i] = (unsigned short)s_cols[i];
    for (int i = threadIdx.x; i < cnt; i += 256) {
        const int m = s_cols[i];
        const int p = atomicAdd(&cnt_in[e * N + m], 1);
        if (p < CAP) idx_in[(size_t)(e * N + m) * CAP + p] = (unsigned short)n;
    }
}

// ---------------------------------------------------------------------------
// K2: hs_out/hs_in = tanh(h @ W_out/W_in + b). 8 nodes per 256-thread block.
// ---------------------------------------------------------------------------
__global__ __launch_bounds__(256) void k_hs(
    const float* __restrict__ h, const float* __restrict__ Wout,
    const float* __restrict__ bout, const float* __restrict__ Win,
    const float* __restrict__ bin, float* __restrict__ hs_out,
    float* __restrict__ hs_in)
{
    __shared__ float hsd[8 * H];
    const int n0 = blockIdx.x * 8;
    const int tid = threadIdx.x;
    const int e = tid >> 6, j = tid & 63;

    for (int idx = tid; idx < 8 * H; idx += 256) hsd[idx] = h[(size_t)n0 * H + idx];
    __syncthreads();

    float aO[8], aI[8];
    {
        const float bO = bout[e * H + j], bI = bin[e * H + j];
        #pragma unroll
        for (int nn = 0; nn < 8; ++nn) { aO[nn] = bO; aI[nn] = bI; }
    }
    for (int k = 0; k < H; ++k) {
        const float wo = Wout[(e * H + k) * H + j];
        const float wi = Win[(e * H + k) * H + j];
        #pragma unroll
        for (int nn = 0; nn < 8; ++nn) {
            const float hv = hsd[nn * H + k];
            aO[nn] += hv * wo;
            aI[nn] += hv * wi;
        }
    }
    #pragma unroll
    for (int nn = 0; nn < 8; ++nn) {
        hs_out[((size_t)e * N + n0 + nn) * H + j] = tanhf(aO[nn]);
        hs_in[((size_t)e * N + n0 + nn) * H + j]  = tanhf(aI[nn]);
    }
}

// ---------------------------------------------------------------------------
// K3: sparse message aggregation (single-pass best version).
// ---------------------------------------------------------------------------
__global__ __launch_bounds__(512) void k_msg(
    const float* __restrict__ hs_out, const float* __restrict__ hs_in,
    const int* __restrict__ cnt_out, const int* __restrict__ cnt_in,
    const unsigned short* __restrict__ idx_out, const unsigned short* __restrict__ idx_in,
    float* __restrict__ msg)
{
    const int n = blockIdx.x;
    const int tid = threadIdx.x;
    const int wv = tid >> 6;             // 0..7
    const int dir = wv >> 2;             // 0=out, 1=in
    const int e = wv & 3;
    const int lane = tid & 63;
    const int g = lane >> 4;             // row-group 0..3
    const int l = lane & 15;             // float4 column within row

    const float4* hs4 = (const float4*)((dir ? hs_in : hs_out) + (size_t)e * N * H);
    const int* cnt = dir ? cnt_in : cnt_out;
    const unsigned short* idx = dir ? idx_in : idx_out;

    const int r = e * N + n;
    const int c = min(cnt[r], CAP);
    const unsigned short* lst = idx + (size_t)r * CAP;

    float ax = 0.f, ay = 0.f, az = 0.f, aw = 0.f;
    int i = g;
    for (; i + 12 < c; i += 16) {
        const int m0 = lst[i];
        const int m1 = lst[i + 4];
        const int m2 = lst[i + 8];
        const int m3 = lst[i + 12];
        const float4 v0 = hs4[(size_t)m0 * (H / 4) + l];
        const float4 v1 = hs4[(size_t)m1 * (H / 4) + l];
        const float4 v2 = hs4[(size_t)m2 * (H / 4) + l];
        const float4 v3 = hs4[(size_t)m3 * (H / 4) + l];
        ax += (v0.x + v1.x) + (v2.x + v3.x);
        ay += (v0.y + v1.y) + (v2.y + v3.y);
        az += (v0.z + v1.z) + (v2.z + v3.z);
        aw += (v0.w + v1.w) + (v2.w + v3.w);
    }
    for (; i < c; i += 4) {
        const float4 v = hs4[(size_t)lst[i] * (H / 4) + l];
        ax += v.x; ay += v.y; az += v.z; aw += v.w;
    }

    ax += __shfl_xor(ax, 16, 64); ay += __shfl_xor(ay, 16, 64);
    az += __shfl_xor(az, 16, 64); aw += __shfl_xor(aw, 16, 64);
    ax += __shfl_xor(ax, 32, 64); ay += __shfl_xor(ay, 32, 64);
    az += __shfl_xor(az, 32, 64); aw += __shfl_xor(aw, 32, 64);

    if (g == 0) {
        float4* mdst = (float4*)msg;
        mdst[(size_t)n * (MSGW / 4) + dir * (E * H / 4) + e * (H / 4) + l] =
            make_float4(ax, ay, az, aw);
    }
}

// ---------------------------------------------------------------------------
// K4 v4: fused GRU.  8 nodes/block, 4 waves = (khalf, node-quad).  Each wave
// computes partial GEMM sums for its 4 nodes over half of K; khalf=1 dumps
// partials to LDS; khalf=0 adds, does gates/LNs, stores.  Grid 625 (2.4
// blocks/CU -> ~10 waves/CU latency hiding; was 313 blocks = 1 wave/SIMD +
// 2x imbalance tail).
// ---------------------------------------------------------------------------
__global__ __launch_bounds__(256) void k_gru(
    const float* __restrict__ msg, const float* __restrict__ h,
    const float* __restrict__ Wih_rz, const float* __restrict__ bih_rz,
    const float* __restrict__ Whh_rz, const float* __restrict__ bhh_rz,
    const float* __restrict__ Wih_c, const float* __restrict__ bih_c,
    const float* __restrict__ Whh_c, const float* __restrict__ bhh_c,
    const float* __restrict__ g_i2h, const float* __restrict__ be_i2h,
    const float* __restrict__ g_h2h, const float* __restrict__ be_h2h,
    const float* __restrict__ g_ci, const float* __restrict__ be_ci,
    const float* __restrict__ g_ch, const float* __restrict__ be_ch,
    float* __restrict__ h_out)
{
    __shared__ float ms[NPB * MSGW];      // 16 KB
    __shared__ float hsd[NPB * H];        // 2 KB
    __shared__ float pb[2][64][12];       // partials from khalf=1 waves, 6 KB
    const int n0 = blockIdx.x * NPB;
    const int tid = threadIdx.x;
    const int j = tid & 63;
    const int wv = tid >> 6;
    const int kh = wv & 1;                // K half
    const int q  = wv >> 1;               // node quad 0/1
    const int nb = q * 4;

    {   // stage msg (8 x 512) + h (8 x 64), zero-fill past N
        const float4* msrc = (const float4*)msg;
        float4* md = (float4*)ms;
        #pragma unroll
        for (int i = 0; i < 4; ++i) {
            const int idx = tid + i * 256;          // 0..1023
            const int n = n0 + (idx >> 7);
            float4 v = make_float4(0.f, 0.f, 0.f, 0.f);
            if (n < N) v = msrc[(size_t)n0 * (MSGW / 4) + idx];
            md[idx] = v;
        }
        if (tid < NPB * H / 4) {
            const float4* hsrc = (const float4*)h;
            float4 v = make_float4(0.f, 0.f, 0.f, 0.f);
            const int n = n0 + (tid >> 4);
            if (n < N) v = hsrc[(size_t)n0 * (H / 4) + tid];
            ((float4*)hsd)[tid] = v;
        }
    }
    __syncthreads();

    const float4* ms4 = (const float4*)ms;
    const float4* hs4 = (const float4*)hsd;

    // ---- x parts over this wave's K half
    float a0[4], a1[4], c0[4];
    {
        const float v0 = kh ? 0.f : bih_rz[j];
        const float v1 = kh ? 0.f : bih_rz[H + j];
        const float vc = kh ? 0.f : bih_c[j];
        #pragma unroll
        for (int i = 0; i < 4; ++i) { a0[i] = v0; a1[i] = v1; c0[i] = vc; }
    }
    {
        const int kq0 = kh * (MSGW / 8);          // 0 or 64
        #pragma unroll 2
        for (int t = 0; t < MSGW / 8; ++t) {
            const int kq = kq0 + t;
            float4 m[4];
            #pragma unroll
            for (int i = 0; i < 4; ++i) m[i] = ms4[(nb + i) * (MSGW / 4) + kq];
            #pragma unroll
            for (int u = 0; u < 4; ++u) {
                const int k = 4 * kq + u;
                const float w0 = Wih_rz[k * GH + j];
                const float w1 = Wih_rz[k * GH + H + j];
                const float wc = Wih_c[k * H + j];
                #pragma unroll
                for (int i = 0; i < 4; ++i) {
                    const float mv = (u == 0) ? m[i].x : (u == 1) ? m[i].y : (u == 2) ? m[i].z : m[i].w;
                    a0[i] += mv * w0;
                    a1[i] += mv * w1;
                    c0[i] += mv * wc;
                }
            }
        }
    }

    // ---- h parts over this wave's K half
    float b0[4], b1[4], ch[4];
    {
        const float v0 = kh ? 0.f : bhh_rz[j];
        const float v1 = kh ? 0.f : bhh_rz[H + j];
        const float vc = kh ? 0.f : bhh_c[j];
        #pragma unroll
        for (int i = 0; i < 4; ++i) { b0[i] = v0; b1[i] = v1; ch[i] = vc; }
    }
    {
        const int kq0 = kh * (H / 8);             // 0 or 8
        #pragma unroll 2
        for (int t = 0; t < H / 8; ++t) {
            const int kq = kq0 + t;
            float4 m[4];
            #pragma unroll
            for (int i = 0; i < 4; ++i) m[i] = hs4[(nb + i) * (H / 4) + kq];
            #pragma unroll
            for (int u = 0; u < 4; ++u) {
                const int k = 4 * kq + u;
                const float w0 = Whh_rz[k * GH + j];
                const float w1 = Whh_rz[k * GH + H + j];
                const float wc = Whh_c[k * H + j];
                #pragma unroll
                for (int i = 0; i < 4; ++i) {
                    const float hv = (u == 0) ? m[i].x : (u == 1) ? m[i].y : (u == 2) ? m[i].z : m[i].w;
                    b0[i] += hv * w0;
                    b1[i] += hv * w1;
                    ch[i] += hv * wc;
                }
            }
        }
    }

    // ---- khalf=1 waves publish partials
    if (kh == 1) {
        #pragma unroll
        for (int i = 0; i < 4; ++i) {
            pb[q][j][i]     = a0[i];
            pb[q][j][4 + i] = a1[i];
            pb[q][j][8 + i] = c0[i];
        }
    }
    __syncthreads();
    if (kh == 1) {
        // reuse pb for the h-part after the first combine round? No: publish
        // b-parts into a second region of pb by overwriting after khalf=0 reads.
    }

    if (kh == 0) {
        #pragma unroll
        for (int i = 0; i < 4; ++i) {
            a0[i] += pb[q][j][i];
            a1[i] += pb[q][j][4 + i];
            c0[i] += pb[q][j][8 + i];
        }
    }
    __syncthreads();
    if (kh == 1) {
        #pragma unroll
        for (int i = 0; i < 4; ++i) {
            pb[q][j][i]     = b0[i];
            pb[q][j][4 + i] = b1[i];
            pb[q][j][8 + i] = ch[i];
        }
    }
    __syncthreads();

    if (kh == 0) {
        #pragma unroll
        for (int i = 0; i < 4; ++i) {
            b0[i] += pb[q][j][i];
            b1[i] += pb[q][j][4 + i];
            ch[i] += pb[q][j][8 + i];
        }

        const float gi0 = g_i2h[j], gi1 = g_i2h[H + j], bi0 = be_i2h[j], bi1 = be_i2h[H + j];
        const float gh0 = g_h2h[j], gh1 = g_h2h[H + j], bh0 = be_h2h[j], bh1 = be_h2h[H + j];
        const float gci = g_ci[j], bci = be_ci[j], gchv = g_ch[j], bchv = be_ch[j];

        #pragma unroll
        for (int i = 0; i < 4; ++i) {
            float s  = wsum(a0[i] + a1[i]);
            float q_ = wsum(a0[i] * a0[i] + a1[i] * a1[i]);
            float mn = s * (1.f / GH);
            float vr = q_ * (1.f / GH) - mn * mn;
            float rs = rsqrtf(vr + 1e-5f);
            float x0 = (a0[i] - mn) * rs * gi0 + bi0;
            float x1 = (a1[i] - mn) * rs * gi1 + bi1;
            float s2  = wsum(b0[i] + b1[i]);
            float q2  = wsum(b0[i] * b0[i] + b1[i] * b1[i]);
            float mn2 = s2 * (1.f / GH);
            float vr2 = q2 * (1.f / GH) - mn2 * mn2;
            float rs2 = rsqrtf(vr2 + 1e-5f);
            float y0 = (b0[i] - mn2) * rs2 * gh0 + bh0;
            float y1 = (b1[i] - mn2) * rs2 * gh1 + bh1;
            const float r_ = 1.f / (1.f + expf(-(x0 + y0)));
            const float z_ = 1.f / (1.f + expf(-(x1 + y1)));

            float s3  = wsum(c0[i]);
            float q3  = wsum(c0[i] * c0[i]);
            float mn3 = s3 * (1.f / H);
            float vr3 = q3 * (1.f / H) - mn3 * mn3;
            float rs3 = rsqrtf(vr3 + 1e-5f);
            float xc = (c0[i] - mn3) * rs3 * gci + bci;
            float s4  = wsum(ch[i]);
            float q4  = wsum(ch[i] * ch[i]);
            float mn4 = s4 * (1.f / H);
            float vr4 = q4 * (1.f / H) - mn4 * mn4;
            float rs4 = rsqrtf(vr4 + 1e-5f);
            float hc = (ch[i] - mn4) * rs4 * gchv + bchv;
            float c  = tanhf(xc + r_ * hc);
            const float hp = hsd[(nb + i) * H + j];
            const int n = n0 + nb + i;
            if (n < N) h_out[(size_t)n * H + j] = z_ * hp + (1.f - z_) * c;
        }
    }
}

// ---------------------------------------------------------------------------
extern "C" void kernel_launch(void* const* d_in, const int* in_sizes, int n_in,
                              void* d_out, int out_size, void* d_ws, size_t ws_size,
                              hipStream_t stream)
{
    const float* A      = (const float*)d_in[0];
    const float* nstate = (const float*)d_in[1];
    // d_in[2] node_ids unused
    const float* nvec   = (const float*)d_in[3];
    const float* nsp    = (const float*)d_in[4];
    const float* Wred   = (const float*)d_in[5];
    const float* bred   = (const float*)d_in[6];
    const float* Winit  = (const float*)d_in[7];
    const float* binit  = (const float*)d_in[8];
    const float* Wout   = (const float*)d_in[9];
    const float* bout   = (const float*)d_in[10];
    const float* Wine   = (const float*)d_in[11];
    const float* bine   = (const float*)d_in[12];
    const float* Wih_rz = (const float*)d_in[13];
    const float* bih_rz = (const float*)d_in[14];
    const float* Whh_rz = (const float*)d_in[15];
    const float* bhh_rz = (const float*)d_in[16];
    const float* Wih_c  = (const float*)d_in[17];
    const float* bih_c  = (const float*)d_in[18];
    const float* Whh_c  = (const float*)d_in[19];
    const float* bhh_c  = (const float*)d_in[20];
    const float* g_i2h  = (const float*)d_in[21];
    const float* be_i2h = (const float*)d_in[22];
    const float* g_h2h  = (const float*)d_in[23];
    const float* be_h2h = (const float*)d_in[24];
    const float* g_ci   = (const float*)d_in[25];
    const float* be_ci  = (const float*)d_in[26];
    const float* g_ch   = (const float*)d_in[27];
    const float* be_ch  = (const float*)d_in[28];

    char* ws = (char*)d_ws;
    size_t off = 0;
    auto alloc = [&](size_t bytes) {
        void* p = ws + off;
        off += (bytes + 255) & ~(size_t)255;
        return p;
    };
    float* h0  = (float*)alloc((size_t)N * H * 4);
    float* h1  = (float*)alloc((size_t)N * H * 4);
    float* hsO = (float*)alloc((size_t)E * N * H * 4);
    float* hsI = (float*)alloc((size_t)E * N * H * 4);
    float* msg = (float*)alloc((size_t)N * MSGW * 4);
    int* cnts  = (int*)alloc((size_t)2 * E * N * 4);
    int* cnt_out = cnts;
    int* cnt_in  = cnts + E * N;
    unsigned short* idxO = (unsigned short*)alloc((size_t)E * N * CAP * 2);
    unsigned short* idxI = (unsigned short*)alloc((size_t)E * N * CAP * 2);

    k_zero<<<(2 * E * N / 4 + 255) / 256, 256, 0, stream>>>((int4*)cnts);
    k_init<<<N / 4, 64, 0, stream>>>(nvec, nstate, nsp, Wred, bred, Winit, binit, h0);
    k_build<<<E * N, 256, 0, stream>>>(A, cnt_out, cnt_in, idxO, idxI);

    const float* hc = h0;
    for (int t = 0; t < 2; ++t) {
        k_hs<<<N / 8, 256, 0, stream>>>(hc, Wout, bout, Wine, bine, hsO, hsI);
        k_msg<<<N, 512, 0, stream>>>(hsO, hsI, cnt_out, cnt_in, idxO, idxI, msg);
        float* hn = (t == 1) ? (float*)d_out : h1;
        k_gru<<<(N + NPB - 1) / NPB, 256, 0, stream>>>(
            msg, hc, Wih_rz, bih_rz, Whh_rz, bhh_rz,
            Wih_c, bih_c, Whh_c, bhh_c,
            g_i2h, be_i2h, g_h2h, be_h2h,
            g_ci, be_ci, g_ch, be_ch, hn);
        hc = hn;
    }
}

// Round 10
// 303.179 us; speedup vs baseline: 35.0126x; 1.1494x over previous
//
#include <hip/hip_runtime.h>
#include <math.h>

#define N    5000
#define E    4
#define H    64
#define PV   300
#define RD   64
#define NS_  8
#define SP_  6
#define NI   (RD + NS_ + SP_)   // 78
#define GH   (2 * H)            // 128
#define MSGW (2 * E * H)        // 512
#define CAP  128
#define NPB  8                  // nodes per k_gru block (4 per wave, 2-way K split)
#define MSG_BPS 256             // k_msg blocks per (dir,e) slice

__device__ __forceinline__ float wsum(float v) {
    v += __shfl_xor(v, 32, 64);
    v += __shfl_xor(v, 16, 64);
    v += __shfl_xor(v, 8, 64);
    v += __shfl_xor(v, 4, 64);
    v += __shfl_xor(v, 2, 64);
    v += __shfl_xor(v, 1, 64);
    return v;
}

// ---------------------------------------------------------------------------
// Kz: zero the count arrays
// ---------------------------------------------------------------------------
__global__ __launch_bounds__(256) void k_zero(int4* __restrict__ p) {
    const int i = blockIdx.x * 256 + threadIdx.x;
    if (i < (2 * E * N) / 4) p[i] = make_int4(0, 0, 0, 0);
}

// ---------------------------------------------------------------------------
// K0: h0 = tanh(concat[tanh(nv@W_red+b_red), node_states, node_sp] @ W_init + b_init)
// ---------------------------------------------------------------------------
__global__ __launch_bounds__(64) void k_init(
    const float* __restrict__ NV, const float* __restrict__ NSt,
    const float* __restrict__ SPos, const float* __restrict__ Wred,
    const float* __restrict__ bred, const float* __restrict__ Winit,
    const float* __restrict__ binit, float* __restrict__ h)
{
    __shared__ float nv[4 * PV];
    __shared__ float ni[4 * NI];
    const int n0 = blockIdx.x * 4;
    const int j = threadIdx.x;

    for (int idx = j; idx < 4 * PV; idx += 64) nv[idx] = NV[(size_t)n0 * PV + idx];
    __syncthreads();

    float acc[4];
    {
        const float br = bred[j];
        #pragma unroll
        for (int nn = 0; nn < 4; ++nn) acc[nn] = br;
    }
    for (int k = 0; k < PV; ++k) {
        const float w = Wred[k * RD + j];
        #pragma unroll
        for (int nn = 0; nn < 4; ++nn) acc[nn] += nv[nn * PV + k] * w;
    }
    #pragma unroll
    for (int nn = 0; nn < 4; ++nn) ni[nn * NI + j] = tanhf(acc[nn]);
    if (j < NS_) {
        #pragma unroll
        for (int nn = 0; nn < 4; ++nn) ni[nn * NI + RD + j] = NSt[(size_t)(n0 + nn) * NS_ + j];
    }
    if (j < SP_) {
        #pragma unroll
        for (int nn = 0; nn < 4; ++nn) ni[nn * NI + RD + NS_ + j] = SPos[(size_t)(n0 + nn) * SP_ + j];
    }
    __syncthreads();

    float a2[4];
    {
        const float bi = binit[j];
        #pragma unroll
        for (int nn = 0; nn < 4; ++nn) a2[nn] = bi;
    }
    for (int k = 0; k < NI; ++k) {
        const float w = Winit[k * H + j];
        #pragma unroll
        for (int nn = 0; nn < 4; ++nn) a2[nn] += ni[nn * NI + k] * w;
    }
    #pragma unroll
    for (int nn = 0; nn < 4; ++nn) h[(size_t)(n0 + nn) * H + j] = tanhf(a2[nn]);
}

// ---------------------------------------------------------------------------
// K1: build out/in adjacency lists (wave-ballot compaction).
// ---------------------------------------------------------------------------
__global__ __launch_bounds__(256) void k_build(
    const float* __restrict__ A, int* __restrict__ cnt_out, int* __restrict__ cnt_in,
    unsigned short* __restrict__ idx_out, unsigned short* __restrict__ idx_in)
{
    const int r = blockIdx.x;          // e*N + n
    const int e = r / N;
    const int n = r - e * N;
    __shared__ int s_cnt;
    __shared__ int s_cols[CAP];
    if (threadIdx.x == 0) s_cnt = 0;
    __syncthreads();

    const float4* row = (const float4*)(A + (size_t)r * N);
    const int lane = threadIdx.x & 63;
    #pragma unroll
    for (int it = 0; it < 5; ++it) {
        const int c = threadIdx.x + it * 256;
        float4 v = make_float4(0.f, 0.f, 0.f, 0.f);
        if (c < N / 4) v = row[c];
        #pragma unroll
        for (int comp = 0; comp < 4; ++comp) {
            const float val = (comp == 0) ? v.x : (comp == 1) ? v.y : (comp == 2) ? v.z : v.w;
            const bool p = (val != 0.f);
            const unsigned long long m = __ballot(p);
            if (m) {
                int base = 0;
                if (lane == 0) base = atomicAdd(&s_cnt, (int)__popcll(m));
                base = __shfl(base, 0, 64);
                if (p) {
                    const int pos = base + (int)__popcll(m & ((1ull << lane) - 1ull));
                    if (pos < CAP) s_cols[pos] = 4 * c + comp;
                }
            }
        }
    }
    __syncthreads();
    const int cnt = min(s_cnt, CAP);
    if (threadIdx.x == 0) cnt_out[r] = cnt;
    for (int i = threadIdx.x; i < cnt; i += 256)
        idx_out[(size_t)r * CAP + i] = (unsigned short)s_cols[i];
    for (int i = threadIdx.x; i < cnt; i += 256) {
        const int m = s_cols[i];
        const int p = atomicAdd(&cnt_in[e * N + m], 1);
        if (p < CAP) idx_in[(size_t)(e * N + m) * CAP + p] = (unsigned short)n;
    }
}

// ---------------------------------------------------------------------------
// K2: hs_out/hs_in = tanh(h @ W_out/W_in + b). 8 nodes per 256-thread block.
// ---------------------------------------------------------------------------
__global__ __launch_bounds__(256) void k_hs(
    const float* __restrict__ h, const float* __restrict__ Wout,
    const float* __restrict__ bout, const float* __restrict__ Win,
    const float* __restrict__ bin, float* __restrict__ hs_out,
    float* __restrict__ hs_in)
{
    __shared__ float hsd[8 * H];
    const int n0 = blockIdx.x * 8;
    const int tid = threadIdx.x;
    const int e = tid >> 6, j = tid & 63;

    for (int idx = tid; idx < 8 * H; idx += 256) hsd[idx] = h[(size_t)n0 * H + idx];
    __syncthreads();

    float aO[8], aI[8];
    {
        const float bO = bout[e * H + j], bI = bin[e * H + j];
        #pragma unroll
        for (int nn = 0; nn < 8; ++nn) { aO[nn] = bO; aI[nn] = bI; }
    }
    for (int k = 0; k < H; ++k) {
        const float wo = Wout[(e * H + k) * H + j];
        const float wi = Win[(e * H + k) * H + j];
        #pragma unroll
        for (int nn = 0; nn < 8; ++nn) {
            const float hv = hsd[nn * H + k];
            aO[nn] += hv * wo;
            aI[nn] += hv * wi;
        }
    }
    #pragma unroll
    for (int nn = 0; nn < 8; ++nn) {
        hs_out[((size_t)e * N + n0 + nn) * H + j] = tanhf(aO[nn]);
        hs_in[((size_t)e * N + n0 + nn) * H + j]  = tanhf(aI[nn]);
    }
}

// ---------------------------------------------------------------------------
// K3 v3: XCD-sliced sparse aggregation.  slice = blockIdx & 7 (HW dispatches
// blocks round-robin over the 8 XCDs, so all blocks of one (dir,e) slice land
// on ONE XCD and its 1.28MB hs slice + idx slice stay L2-resident; was 146MB
// of L2-miss traffic per launch).  4 waves/block, grid-stride over nodes.
// Per-node gather order identical to v2 -> bit-identical msg.
// ---------------------------------------------------------------------------
__global__ __launch_bounds__(256) void k_msg(
    const float* __restrict__ hs_out, const float* __restrict__ hs_in,
    const int* __restrict__ cnt_out, const int* __restrict__ cnt_in,
    const unsigned short* __restrict__ idx_out, const unsigned short* __restrict__ idx_in,
    float* __restrict__ msg)
{
    const int slice = blockIdx.x & 7;    // -> one XCD per slice (round-robin)
    const int sb = blockIdx.x >> 3;      // block index within slice
    const int dir = slice >> 2;
    const int e = slice & 3;
    const int tid = threadIdx.x;
    const int wv = tid >> 6;             // 0..3
    const int lane = tid & 63;
    const int g = lane >> 4;             // row-group 0..3
    const int l = lane & 15;             // float4 column within row

    const float4* hs4 = (const float4*)((dir ? hs_in : hs_out) + (size_t)e * N * H);
    const int* cnt = (dir ? cnt_in : cnt_out) + e * N;
    const unsigned short* idx = (dir ? idx_in : idx_out) + (size_t)e * N * CAP;
    float4* mdst = (float4*)msg;

    for (int n = sb * 4 + wv; n < N; n += MSG_BPS * 4) {
        const int c = min(cnt[n], CAP);
        const unsigned short* lst = idx + (size_t)n * CAP;

        float ax = 0.f, ay = 0.f, az = 0.f, aw = 0.f;
        int i = g;
        for (; i + 12 < c; i += 16) {
            const int m0 = lst[i];
            const int m1 = lst[i + 4];
            const int m2 = lst[i + 8];
            const int m3 = lst[i + 12];
            const float4 v0 = hs4[(size_t)m0 * (H / 4) + l];
            const float4 v1 = hs4[(size_t)m1 * (H / 4) + l];
            const float4 v2 = hs4[(size_t)m2 * (H / 4) + l];
            const float4 v3 = hs4[(size_t)m3 * (H / 4) + l];
            ax += (v0.x + v1.x) + (v2.x + v3.x);
            ay += (v0.y + v1.y) + (v2.y + v3.y);
            az += (v0.z + v1.z) + (v2.z + v3.z);
            aw += (v0.w + v1.w) + (v2.w + v3.w);
        }
        for (; i < c; i += 4) {
            const float4 v = hs4[(size_t)lst[i] * (H / 4) + l];
            ax += v.x; ay += v.y; az += v.z; aw += v.w;
        }

        ax += __shfl_xor(ax, 16, 64); ay += __shfl_xor(ay, 16, 64);
        az += __shfl_xor(az, 16, 64); aw += __shfl_xor(aw, 16, 64);
        ax += __shfl_xor(ax, 32, 64); ay += __shfl_xor(ay, 32, 64);
        az += __shfl_xor(az, 32, 64); aw += __shfl_xor(aw, 32, 64);

        if (g == 0) {
            mdst[(size_t)n * (MSGW / 4) + dir * (E * H / 4) + e * (H / 4) + l] =
                make_float4(ax, ay, az, aw);
        }
    }
}

// ---------------------------------------------------------------------------
// K4 v4: fused GRU.  8 nodes/block, 4 waves = (khalf, node-quad), 2-way K
// split with LDS partial combine.  Grid 625.
// ---------------------------------------------------------------------------
__global__ __launch_bounds__(256) void k_gru(
    const float* __restrict__ msg, const float* __restrict__ h,
    const float* __restrict__ Wih_rz, const float* __restrict__ bih_rz,
    const float* __restrict__ Whh_rz, const float* __restrict__ bhh_rz,
    const float* __restrict__ Wih_c, const float* __restrict__ bih_c,
    const float* __restrict__ Whh_c, const float* __restrict__ bhh_c,
    const float* __restrict__ g_i2h, const float* __restrict__ be_i2h,
    const float* __restrict__ g_h2h, const float* __restrict__ be_h2h,
    const float* __restrict__ g_ci, const float* __restrict__ be_ci,
    const float* __restrict__ g_ch, const float* __restrict__ be_ch,
    float* __restrict__ h_out)
{
    __shared__ float ms[NPB * MSGW];      // 16 KB
    __shared__ float hsd[NPB * H];        // 2 KB
    __shared__ float pb[2][64][12];       // partials from khalf=1 waves, 6 KB
    const int n0 = blockIdx.x * NPB;
    const int tid = threadIdx.x;
    const int j = tid & 63;
    const int wv = tid >> 6;
    const int kh = wv & 1;                // K half
    const int q  = wv >> 1;               // node quad 0/1
    const int nb = q * 4;

    {   // stage msg (8 x 512) + h (8 x 64), zero-fill past N
        const float4* msrc = (const float4*)msg;
        float4* md = (float4*)ms;
        #pragma unroll
        for (int i = 0; i < 4; ++i) {
            const int idx = tid + i * 256;          // 0..1023
            const int n = n0 + (idx >> 7);
            float4 v = make_float4(0.f, 0.f, 0.f, 0.f);
            if (n < N) v = msrc[(size_t)n0 * (MSGW / 4) + idx];
            md[idx] = v;
        }
        if (tid < NPB * H / 4) {
            const float4* hsrc = (const float4*)h;
            float4 v = make_float4(0.f, 0.f, 0.f, 0.f);
            const int n = n0 + (tid >> 4);
            if (n < N) v = hsrc[(size_t)n0 * (H / 4) + tid];
            ((float4*)hsd)[tid] = v;
        }
    }
    __syncthreads();

    const float4* ms4 = (const float4*)ms;
    const float4* hs4 = (const float4*)hsd;

    // ---- x parts over this wave's K half
    float a0[4], a1[4], c0[4];
    {
        const float v0 = kh ? 0.f : bih_rz[j];
        const float v1 = kh ? 0.f : bih_rz[H + j];
        const float vc = kh ? 0.f : bih_c[j];
        #pragma unroll
        for (int i = 0; i < 4; ++i) { a0[i] = v0; a1[i] = v1; c0[i] = vc; }
    }
    {
        const int kq0 = kh * (MSGW / 8);          // 0 or 64
        #pragma unroll 2
        for (int t = 0; t < MSGW / 8; ++t) {
            const int kq = kq0 + t;
            float4 m[4];
            #pragma unroll
            for (int i = 0; i < 4; ++i) m[i] = ms4[(nb + i) * (MSGW / 4) + kq];
            #pragma unroll
            for (int u = 0; u < 4; ++u) {
                const int k = 4 * kq + u;
                const float w0 = Wih_rz[k * GH + j];
                const float w1 = Wih_rz[k * GH + H + j];
                const float wc = Wih_c[k * H + j];
                #pragma unroll
                for (int i = 0; i < 4; ++i) {
                    const float mv = (u == 0) ? m[i].x : (u == 1) ? m[i].y : (u == 2) ? m[i].z : m[i].w;
                    a0[i] += mv * w0;
                    a1[i] += mv * w1;
                    c0[i] += mv * wc;
                }
            }
        }
    }

    // ---- h parts over this wave's K half
    float b0[4], b1[4], ch[4];
    {
        const float v0 = kh ? 0.f : bhh_rz[j];
        const float v1 = kh ? 0.f : bhh_rz[H + j];
        const float vc = kh ? 0.f : bhh_c[j];
        #pragma unroll
        for (int i = 0; i < 4; ++i) { b0[i] = v0; b1[i] = v1; ch[i] = vc; }
    }
    {
        const int kq0 = kh * (H / 8);             // 0 or 8
        #pragma unroll 2
        for (int t = 0; t < H / 8; ++t) {
            const int kq = kq0 + t;
            float4 m[4];
            #pragma unroll
            for (int i = 0; i < 4; ++i) m[i] = hs4[(nb + i) * (H / 4) + kq];
            #pragma unroll
            for (int u = 0; u < 4; ++u) {
                const int k = 4 * kq + u;
                const float w0 = Whh_rz[k * GH + j];
                const float w1 = Whh_rz[k * GH + H + j];
                const float wc = Whh_c[k * H + j];
                #pragma unroll
                for (int i = 0; i < 4; ++i) {
                    const float hv = (u == 0) ? m[i].x : (u == 1) ? m[i].y : (u == 2) ? m[i].z : m[i].w;
                    b0[i] += hv * w0;
                    b1[i] += hv * w1;
                    ch[i] += hv * wc;
                }
            }
        }
    }

    // ---- khalf=1 waves publish x partials; khalf=0 combines
    if (kh == 1) {
        #pragma unroll
        for (int i = 0; i < 4; ++i) {
            pb[q][j][i]     = a0[i];
            pb[q][j][4 + i] = a1[i];
            pb[q][j][8 + i] = c0[i];
        }
    }
    __syncthreads();
    if (kh == 0) {
        #pragma unroll
        for (int i = 0; i < 4; ++i) {
            a0[i] += pb[q][j][i];
            a1[i] += pb[q][j][4 + i];
            c0[i] += pb[q][j][8 + i];
        }
    }
    __syncthreads();
    if (kh == 1) {
        #pragma unroll
        for (int i = 0; i < 4; ++i) {
            pb[q][j][i]     = b0[i];
            pb[q][j][4 + i] = b1[i];
            pb[q][j][8 + i] = ch[i];
        }
    }
    __syncthreads();

    if (kh == 0) {
        #pragma unroll
        for (int i = 0; i < 4; ++i) {
            b0[i] += pb[q][j][i];
            b1[i] += pb[q][j][4 + i];
            ch[i] += pb[q][j][8 + i];
        }

        const float gi0 = g_i2h[j], gi1 = g_i2h[H + j], bi0 = be_i2h[j], bi1 = be_i2h[H + j];
        const float gh0 = g_h2h[j], gh1 = g_h2h[H + j], bh0 = be_h2h[j], bh1 = be_h2h[H + j];
        const float gci = g_ci[j], bci = be_ci[j], gchv = g_ch[j], bchv = be_ch[j];

        #pragma unroll
        for (int i = 0; i < 4; ++i) {
            float s  = wsum(a0[i] + a1[i]);
            float q_ = wsum(a0[i] * a0[i] + a1[i] * a1[i]);
            float mn = s * (1.f / GH);
            float vr = q_ * (1.f / GH) - mn * mn;
            float rs = rsqrtf(vr + 1e-5f);
            float x0 = (a0[i] - mn) * rs * gi0 + bi0;
            float x1 = (a1[i] - mn) * rs * gi1 + bi1;
            float s2  = wsum(b0[i] + b1[i]);
            float q2  = wsum(b0[i] * b0[i] + b1[i] * b1[i]);
            float mn2 = s2 * (1.f / GH);
            float vr2 = q2 * (1.f / GH) - mn2 * mn2;
            float rs2 = rsqrtf(vr2 + 1e-5f);
            float y0 = (b0[i] - mn2) * rs2 * gh0 + bh0;
            float y1 = (b1[i] - mn2) * rs2 * gh1 + bh1;
            const float r_ = 1.f / (1.f + expf(-(x0 + y0)));
            const float z_ = 1.f / (1.f + expf(-(x1 + y1)));

            float s3  = wsum(c0[i]);
            float q3  = wsum(c0[i] * c0[i]);
            float mn3 = s3 * (1.f / H);
            float vr3 = q3 * (1.f / H) - mn3 * mn3;
            float rs3 = rsqrtf(vr3 + 1e-5f);
            float xc = (c0[i] - mn3) * rs3 * gci + bci;
            float s4  = wsum(ch[i]);
            float q4  = wsum(ch[i] * ch[i]);
            float mn4 = s4 * (1.f / H);
            float vr4 = q4 * (1.f / H) - mn4 * mn4;
            float rs4 = rsqrtf(vr4 + 1e-5f);
            float hc = (ch[i] - mn4) * rs4 * gchv + bchv;
            float c  = tanhf(xc + r_ * hc);
            const float hp = hsd[(nb + i) * H + j];
            const int n = n0 + nb + i;
            if (n < N) h_out[(size_t)n * H + j] = z_ * hp + (1.f - z_) * c;
        }
    }
}

// ---------------------------------------------------------------------------
extern "C" void kernel_launch(void* const* d_in, const int* in_sizes, int n_in,
                              void* d_out, int out_size, void* d_ws, size_t ws_size,
                              hipStream_t stream)
{
    const float* A      = (const float*)d_in[0];
    const float* nstate = (const float*)d_in[1];
    // d_in[2] node_ids unused
    const float* nvec   = (const float*)d_in[3];
    const float* nsp    = (const float*)d_in[4];
    const float* Wred   = (const float*)d_in[5];
    const float* bred   = (const float*)d_in[6];
    const float* Winit  = (const float*)d_in[7];
    const float* binit  = (const float*)d_in[8];
    const float* Wout   = (const float*)d_in[9];
    const float* bout   = (const float*)d_in[10];
    const float* Wine   = (const float*)d_in[11];
    const float* bine   = (const float*)d_in[12];
    const float* Wih_rz = (const float*)d_in[13];
    const float* bih_rz = (const float*)d_in[14];
    const float* Whh_rz = (const float*)d_in[15];
    const float* bhh_rz = (const float*)d_in[16];
    const float* Wih_c  = (const float*)d_in[17];
    const float* bih_c  = (const float*)d_in[18];
    const float* Whh_c  = (const float*)d_in[19];
    const float* bhh_c  = (const float*)d_in[20];
    const float* g_i2h  = (const float*)d_in[21];
    const float* be_i2h = (const float*)d_in[22];
    const float* g_h2h  = (const float*)d_in[23];
    const float* be_h2h = (const float*)d_in[24];
    const float* g_ci   = (const float*)d_in[25];
    const float* be_ci  = (const float*)d_in[26];
    const float* g_ch   = (const float*)d_in[27];
    const float* be_ch  = (const float*)d_in[28];

    char* ws = (char*)d_ws;
    size_t off = 0;
    auto alloc = [&](size_t bytes) {
        void* p = ws + off;
        off += (bytes + 255) & ~(size_t)255;
        return p;
    };
    float* h0  = (float*)alloc((size_t)N * H * 4);
    float* h1  = (float*)alloc((size_t)N * H * 4);
    float* hsO = (float*)alloc((size_t)E * N * H * 4);
    float* hsI = (float*)alloc((size_t)E * N * H * 4);
    float* msg = (float*)alloc((size_t)N * MSGW * 4);
    int* cnts  = (int*)alloc((size_t)2 * E * N * 4);
    int* cnt_out = cnts;
    int* cnt_in  = cnts + E * N;
    unsigned short* idxO = (unsigned short*)alloc((size_t)E * N * CAP * 2);
    unsigned short* idxI = (unsigned short*)alloc((size_t)E * N * CAP * 2);

    k_zero<<<(2 * E * N / 4 + 255) / 256, 256, 0, stream>>>((int4*)cnts);
    k_init<<<N / 4, 64, 0, stream>>>(nvec, nstate, nsp, Wred, bred, Winit, binit, h0);
    k_build<<<E * N, 256, 0, stream>>>(A, cnt_out, cnt_in, idxO, idxI);

    const float* hc = h0;
    for (int t = 0; t < 2; ++t) {
        k_hs<<<N / 8, 256, 0, stream>>>(hc, Wout, bout, Wine, bine, hsO, hsI);
        k_msg<<<8 * MSG_BPS, 256, 0, stream>>>(hsO, hsI, cnt_out, cnt_in, idxO, idxI, msg);
        float* hn = (t == 1) ? (float*)d_out : h1;
        k_gru<<<(N + NPB - 1) / NPB, 256, 0, stream>>>(
            msg, hc, Wih_rz, bih_rz, Whh_rz, bhh_rz,
            Wih_c, bih_c, Whh_c, bhh_c,
            g_i2h, be_i2h, g_h2h, be_h2h,
            g_ci, be_ci, g_ch, be_ch, hn);
        hc = hn;
    }
}